// Round 1
// baseline (2309.933 us; speedup 1.0000x reference)
//
#include <hip/hip_runtime.h>

// ---------------- degree / norm ----------------
__global__ void deg_kernel(const int* __restrict__ src, const int* __restrict__ dst,
                           float* __restrict__ dout, float* __restrict__ din, int E) {
  int e = blockIdx.x * blockDim.x + threadIdx.x;
  if (e >= E) return;
  atomicAdd(&dout[src[e]], 1.0f);
  atomicAdd(&din[dst[e]], 1.0f);
}

__global__ void norm_kernel(const float* __restrict__ dout, const float* __restrict__ din,
                            float* __restrict__ nout, float* __restrict__ nin, int N) {
  int i = blockIdx.x * blockDim.x + threadIdx.x;
  if (i >= N) return;
  float o = dout[i], d = din[i];
  nout[i] = o > 0.f ? rsqrtf(fmaxf(o, 1.f)) : 0.f;
  nin[i]  = d > 0.f ? rsqrtf(fmaxf(d, 1.f)) : 0.f;
}

// ---------------- edge scatter (16 lanes / edge, float4) ----------------
__global__ void edge_msg(const int* __restrict__ src, const int* __restrict__ dst,
                         const float* __restrict__ x, const float* __restrict__ nout,
                         float* __restrict__ agg, int E) {
  int t = blockIdx.x * blockDim.x + threadIdx.x;
  int e = t >> 4;
  if (e >= E) return;
  int lane = t & 15;
  int s = src[e], d = dst[e];
  float c = nout[s];
  float4 v = *reinterpret_cast<const float4*>(x + (size_t)s * 64 + lane * 4);
  float* base = agg + (size_t)d * 64 + lane * 4;
  atomicAdd(base + 0, v.x * c);
  atomicAdd(base + 1, v.y * c);
  atomicAdd(base + 2, v.z * c);
  atomicAdd(base + 3, v.w * c);
}

// ---------------- layer-1 epilogue: h1 = relu(agg*nin + b1); out = h1 ----------------
__global__ void post1_kernel(const float* __restrict__ agg, const float* __restrict__ nin,
                             const float* __restrict__ bias, float* __restrict__ h,
                             float* __restrict__ out, int N) {
  int i = blockIdx.x * blockDim.x + threadIdx.x;
  if (i >= N * 16) return;
  int node = i >> 4;
  int c4 = (i & 15) * 4;
  float s = nin[node];
  float4 v = *reinterpret_cast<const float4*>(agg + (size_t)node * 64 + c4);
  float4 b = *reinterpret_cast<const float4*>(bias + c4);
  float4 r;
  r.x = fmaxf(v.x * s + b.x, 0.f);
  r.y = fmaxf(v.y * s + b.y, 0.f);
  r.z = fmaxf(v.z * s + b.z, 0.f);
  r.w = fmaxf(v.w * s + b.w, 0.f);
  *reinterpret_cast<float4*>(h + (size_t)node * 64 + c4) = r;
  *reinterpret_cast<float4*>(out + (size_t)node * 64 + c4) = r;
}

// ---------------- tiled GEMM: C[M x 64] = (rowscale? diag(s)*A : A)[M x K] @ B[K x 64]
// FUSED: C = relu(AB + bias); out = max(out, C). Else: raw store.
template <int K, bool SCALE, bool FUSED>
__global__ __launch_bounds__(256) void gemm_kernel(
    const float* __restrict__ A, const float* __restrict__ B,
    const float* __restrict__ rowscale, const float* __restrict__ bias,
    float* __restrict__ C, float* __restrict__ out, int M) {
  __shared__ float sA[64][K + 4];   // +4 pad: breaks stride-K bank aliasing, keeps 16B align
  __shared__ float sB[K][64];
  const int t = threadIdx.x;
  const int row0 = blockIdx.x * 64;

  // stage A tile (scaled), zero-fill OOB rows
  for (int i = t * 4; i < 64 * K; i += 256 * 4) {
    int r = i / K, c = i % K;
    int gr = row0 + r;
    float4 v = make_float4(0.f, 0.f, 0.f, 0.f);
    if (gr < M) {
      v = *reinterpret_cast<const float4*>(A + (size_t)gr * K + c);
      if (SCALE) {
        float s = rowscale[gr];
        v.x *= s; v.y *= s; v.z *= s; v.w *= s;
      }
    }
    *reinterpret_cast<float4*>(&sA[r][c]) = v;
  }
  // stage B (row-major [K][64] matches input layout)
  for (int i = t * 4; i < K * 64; i += 256 * 4) {
    *reinterpret_cast<float4*>(&sB[0][0] + i) = *reinterpret_cast<const float4*>(B + i);
  }
  __syncthreads();

  const int ty = t >> 4;   // 0..15 -> rows ty*4 .. ty*4+3
  const int tx = t & 15;   // 0..15 -> cols tx*4 .. tx*4+3
  float acc[4][4] = {};
#pragma unroll 8
  for (int k = 0; k < K; ++k) {
    float a[4];
#pragma unroll
    for (int i = 0; i < 4; ++i) a[i] = sA[ty * 4 + i][k];
    float4 b = *reinterpret_cast<float4*>(&sB[k][tx * 4]);
#pragma unroll
    for (int i = 0; i < 4; ++i) {
      acc[i][0] += a[i] * b.x;
      acc[i][1] += a[i] * b.y;
      acc[i][2] += a[i] * b.z;
      acc[i][3] += a[i] * b.w;
    }
  }

#pragma unroll
  for (int i = 0; i < 4; ++i) {
    int gr = row0 + ty * 4 + i;
    if (gr >= M) continue;
    float4 v = make_float4(acc[i][0], acc[i][1], acc[i][2], acc[i][3]);
    size_t off = (size_t)gr * 64 + tx * 4;
    if (FUSED) {
      float4 b = *reinterpret_cast<const float4*>(bias + tx * 4);
      v.x = fmaxf(v.x + b.x, 0.f);
      v.y = fmaxf(v.y + b.y, 0.f);
      v.z = fmaxf(v.z + b.z, 0.f);
      v.w = fmaxf(v.w + b.w, 0.f);
      *reinterpret_cast<float4*>(C + off) = v;
      float4 o = *reinterpret_cast<float4*>(out + off);
      o.x = fmaxf(o.x, v.x);
      o.y = fmaxf(o.y, v.y);
      o.z = fmaxf(o.z, v.z);
      o.w = fmaxf(o.w, v.w);
      *reinterpret_cast<float4*>(out + off) = o;
    } else {
      *reinterpret_cast<float4*>(C + off) = v;
    }
  }
}

extern "C" void kernel_launch(void* const* d_in, const int* in_sizes, int n_in,
                              void* d_out, int out_size, void* d_ws, size_t ws_size,
                              hipStream_t stream) {
  const float* feat = (const float*)d_in[0];
  const int* src    = (const int*)d_in[1];
  const int* dst    = (const int*)d_in[2];
  const float* W1   = (const float*)d_in[3];
  const float* b1   = (const float*)d_in[4];
  const float* W2   = (const float*)d_in[5];
  const float* b2   = (const float*)d_in[6];
  const float* W3   = (const float*)d_in[7];
  const float* b3   = (const float*)d_in[8];
  float* out = (float*)d_out;

  const int N = in_sizes[0] / 128;
  const int E = in_sizes[1];

  float* ws      = (float*)d_ws;
  float* deg_out = ws;                       // N
  float* deg_in  = ws + (size_t)N;           // N
  float* nout    = ws + 2 * (size_t)N;       // N
  float* nin     = ws + 3 * (size_t)N;       // N
  float* tmp     = ws + 4 * (size_t)N;       // N*64  (X1, then h1, h2, h3)
  float* agg     = tmp + 64 * (size_t)N;     // N*64

  // degrees + norms
  hipMemsetAsync(deg_out, 0, 2 * (size_t)N * sizeof(float), stream);
  deg_kernel<<<(E + 255) / 256, 256, 0, stream>>>(src, dst, deg_out, deg_in, E);
  norm_kernel<<<(N + 255) / 256, 256, 0, stream>>>(deg_out, deg_in, nout, nin, N);

  const int gemm_blocks = (N + 63) / 64;
  const int edge_blocks = (int)(((size_t)E * 16 + 255) / 256);
  const int post_blocks = (N * 16 + 255) / 256;

  // ---- layer 1: X1 = feat@W1; agg = scatter(X1*nout[src] -> dst); h1 = relu(agg*nin + b1); out = h1
  gemm_kernel<128, false, false><<<gemm_blocks, 256, 0, stream>>>(feat, W1, nullptr, nullptr, tmp, nullptr, N);
  hipMemsetAsync(agg, 0, (size_t)N * 64 * sizeof(float), stream);
  edge_msg<<<edge_blocks, 256, 0, stream>>>(src, dst, tmp, nout, agg, E);
  post1_kernel<<<post_blocks, 256, 0, stream>>>(agg, nin, b1, tmp, out, N);

  // ---- layer 2: agg = scatter(h1); h2 = relu((agg*nin)@W2 + b2); out = max(out, h2)
  hipMemsetAsync(agg, 0, (size_t)N * 64 * sizeof(float), stream);
  edge_msg<<<edge_blocks, 256, 0, stream>>>(src, dst, tmp, nout, agg, E);
  gemm_kernel<64, true, true><<<gemm_blocks, 256, 0, stream>>>(agg, W2, nin, b2, tmp, out, N);

  // ---- layer 3: agg = scatter(h2); h3 = relu((agg*nin)@W3 + b3); out = max(out, h3)
  hipMemsetAsync(agg, 0, (size_t)N * 64 * sizeof(float), stream);
  edge_msg<<<edge_blocks, 256, 0, stream>>>(src, dst, tmp, nout, agg, E);
  gemm_kernel<64, true, true><<<gemm_blocks, 256, 0, stream>>>(agg, W3, nin, b3, tmp, out, N);
}

// Round 2
// 312.641 us; speedup vs baseline: 7.3885x; 7.3885x over previous
//
#include <hip/hip_runtime.h>

// ================= degrees =================
__global__ void deg_kernel(const int* __restrict__ src, const int* __restrict__ dst,
                           int* __restrict__ odeg, int* __restrict__ ideg, int E) {
  int e = blockIdx.x * blockDim.x + threadIdx.x;
  if (e >= E) return;
  atomicAdd(&odeg[src[e]], 1);
  atomicAdd(&ideg[dst[e]], 1);
}

__global__ void norm_kernel(const int* __restrict__ odeg, const int* __restrict__ ideg,
                            float* __restrict__ nout, float* __restrict__ nin, int N) {
  int i = blockIdx.x * blockDim.x + threadIdx.x;
  if (i >= N) return;
  int o = odeg[i], d = ideg[i];
  nout[i] = o > 0 ? rsqrtf((float)o) : 0.f;
  nin[i]  = d > 0 ? rsqrtf((float)d) : 0.f;
}

// ================= exclusive scan (hierarchical) =================
__global__ void scan1(const int* __restrict__ cnt, int* __restrict__ excl,
                      int* __restrict__ bsums, int N) {
  __shared__ int s[256];
  int i = blockIdx.x * 256 + threadIdx.x;
  int v = (i < N) ? cnt[i] : 0;
  s[threadIdx.x] = v;
  __syncthreads();
#pragma unroll
  for (int off = 1; off < 256; off <<= 1) {
    int tv = 0;
    if (threadIdx.x >= off) tv = s[threadIdx.x - off];
    __syncthreads();
    if (threadIdx.x >= off) s[threadIdx.x] += tv;
    __syncthreads();
  }
  if (i < N) excl[i] = s[threadIdx.x] - v;
  if (threadIdx.x == 255) bsums[blockIdx.x] = s[255];
}

__global__ void scan_top(int* __restrict__ bsums, int nb) {
  __shared__ int s[256];
  __shared__ int run_s;
  if (threadIdx.x == 0) run_s = 0;
  __syncthreads();
  for (int base = 0; base < nb; base += 256) {
    int i = base + threadIdx.x;
    int v = (i < nb) ? bsums[i] : 0;
    s[threadIdx.x] = v;
    __syncthreads();
#pragma unroll
    for (int off = 1; off < 256; off <<= 1) {
      int tv = 0;
      if (threadIdx.x >= off) tv = s[threadIdx.x - off];
      __syncthreads();
      if (threadIdx.x >= off) s[threadIdx.x] += tv;
      __syncthreads();
    }
    int run = run_s;
    if (i < nb) bsums[i] = run + s[threadIdx.x] - v;
    __syncthreads();
    if (threadIdx.x == 0) run_s = run + s[255];
    __syncthreads();
  }
}

__global__ void add_off(int* __restrict__ rowptr, const int* __restrict__ bsums, int N, int E) {
  int i = blockIdx.x * 256 + threadIdx.x;
  if (i < N) rowptr[i] += bsums[blockIdx.x];
  if (blockIdx.x == 0 && threadIdx.x == 0) rowptr[N] = E;
}

// ================= CSR fill (counting sort by dst) =================
__global__ void fill_csr(const int* __restrict__ src, const int* __restrict__ dst,
                         const int* __restrict__ rowptr, int* __restrict__ cursor,
                         int* __restrict__ csr, int E) {
  int e = blockIdx.x * blockDim.x + threadIdx.x;
  if (e >= E) return;
  int d = dst[e];
  int pos = atomicAdd(&cursor[d], 1);
  csr[rowptr[d] + pos] = src[e];
}

// ================= gather aggregation (16 lanes / node, float4) =================
// x is already pre-scaled by nout[src] on the producer side.
// L1: y = relu(acc*nin + bias) * nout  (next-layer input), out = relu(...)
// else: y = raw acc
template <bool L1>
__global__ void agg_kernel(const int* __restrict__ rowptr, const int* __restrict__ csr,
                           const float* __restrict__ x, const float* __restrict__ nin,
                           const float* __restrict__ bias, const float* __restrict__ nout,
                           float* __restrict__ y, float* __restrict__ out, int N) {
  int t = blockIdx.x * blockDim.x + threadIdx.x;
  int node = t >> 4;
  if (node >= N) return;
  int lane = t & 15;
  int b = rowptr[node], e = rowptr[node + 1];
  float4 acc = make_float4(0.f, 0.f, 0.f, 0.f);
  for (int i = b; i < e; ++i) {
    int s = csr[i];
    float4 v = *reinterpret_cast<const float4*>(x + (size_t)s * 64 + lane * 4);
    acc.x += v.x; acc.y += v.y; acc.z += v.z; acc.w += v.w;
  }
  size_t off = (size_t)node * 64 + lane * 4;
  if (L1) {
    float s = nin[node];
    float4 bb = *reinterpret_cast<const float4*>(bias + lane * 4);
    float4 h;
    h.x = fmaxf(acc.x * s + bb.x, 0.f);
    h.y = fmaxf(acc.y * s + bb.y, 0.f);
    h.z = fmaxf(acc.z * s + bb.z, 0.f);
    h.w = fmaxf(acc.w * s + bb.w, 0.f);
    *reinterpret_cast<float4*>(out + off) = h;
    float no = nout[node];
    h.x *= no; h.y *= no; h.z *= no; h.w *= no;
    *reinterpret_cast<float4*>(y + off) = h;
  } else {
    *reinterpret_cast<float4*>(y + off) = acc;
  }
}

// ================= tiled GEMM: C[M x 64] = (INSCALE? diag(nin)*A : A)[M x K] @ B[K x 64]
// FUSED: h = relu(AB + bias); out = max(out, h); C = (OUTS? h*nout : h) if WRITEC
// !FUSED: C = (OUTS? v*nout : v)
template <int K, bool INSCALE, bool FUSED, bool OUTS, bool WRITEC>
__global__ __launch_bounds__(256) void gemm_kernel(
    const float* __restrict__ A, const float* __restrict__ B,
    const float* __restrict__ nin, const float* __restrict__ bias,
    const float* __restrict__ nout,
    float* __restrict__ C, float* __restrict__ out, int M) {
  __shared__ float sA[64][K + 4];
  __shared__ float sB[K][64];
  const int t = threadIdx.x;
  const int row0 = blockIdx.x * 64;

  for (int i = t * 4; i < 64 * K; i += 256 * 4) {
    int r = i / K, c = i % K;
    int gr = row0 + r;
    float4 v = make_float4(0.f, 0.f, 0.f, 0.f);
    if (gr < M) {
      v = *reinterpret_cast<const float4*>(A + (size_t)gr * K + c);
      if (INSCALE) {
        float s = nin[gr];
        v.x *= s; v.y *= s; v.z *= s; v.w *= s;
      }
    }
    *reinterpret_cast<float4*>(&sA[r][c]) = v;
  }
  for (int i = t * 4; i < K * 64; i += 256 * 4) {
    *reinterpret_cast<float4*>(&sB[0][0] + i) = *reinterpret_cast<const float4*>(B + i);
  }
  __syncthreads();

  const int ty = t >> 4;
  const int tx = t & 15;
  float acc[4][4] = {};
#pragma unroll 8
  for (int k = 0; k < K; ++k) {
    float a[4];
#pragma unroll
    for (int i = 0; i < 4; ++i) a[i] = sA[ty * 4 + i][k];
    float4 b = *reinterpret_cast<float4*>(&sB[k][tx * 4]);
#pragma unroll
    for (int i = 0; i < 4; ++i) {
      acc[i][0] += a[i] * b.x;
      acc[i][1] += a[i] * b.y;
      acc[i][2] += a[i] * b.z;
      acc[i][3] += a[i] * b.w;
    }
  }

#pragma unroll
  for (int i = 0; i < 4; ++i) {
    int gr = row0 + ty * 4 + i;
    if (gr >= M) continue;
    float4 v = make_float4(acc[i][0], acc[i][1], acc[i][2], acc[i][3]);
    size_t off = (size_t)gr * 64 + tx * 4;
    if (FUSED) {
      float4 b = *reinterpret_cast<const float4*>(bias + tx * 4);
      float4 h;
      h.x = fmaxf(v.x + b.x, 0.f);
      h.y = fmaxf(v.y + b.y, 0.f);
      h.z = fmaxf(v.z + b.z, 0.f);
      h.w = fmaxf(v.w + b.w, 0.f);
      float4 o = *reinterpret_cast<float4*>(out + off);
      o.x = fmaxf(o.x, h.x);
      o.y = fmaxf(o.y, h.y);
      o.z = fmaxf(o.z, h.z);
      o.w = fmaxf(o.w, h.w);
      *reinterpret_cast<float4*>(out + off) = o;
      if (WRITEC) {
        if (OUTS) {
          float no = nout[gr];
          h.x *= no; h.y *= no; h.z *= no; h.w *= no;
        }
        *reinterpret_cast<float4*>(C + off) = h;
      }
    } else {
      if (OUTS) {
        float no = nout[gr];
        v.x *= no; v.y *= no; v.z *= no; v.w *= no;
      }
      *reinterpret_cast<float4*>(C + off) = v;
    }
  }
}

extern "C" void kernel_launch(void* const* d_in, const int* in_sizes, int n_in,
                              void* d_out, int out_size, void* d_ws, size_t ws_size,
                              hipStream_t stream) {
  const float* feat = (const float*)d_in[0];
  const int* src    = (const int*)d_in[1];
  const int* dst    = (const int*)d_in[2];
  const float* W1   = (const float*)d_in[3];
  const float* b1   = (const float*)d_in[4];
  const float* W2   = (const float*)d_in[5];
  const float* b2   = (const float*)d_in[6];
  const float* W3   = (const float*)d_in[7];
  const float* b3   = (const float*)d_in[8];
  float* out = (float*)d_out;

  const int N = in_sizes[0] / 128;
  const int E = in_sizes[1];

  // ---- workspace layout (all 4B elements; float4 regions 16B-aligned) ----
  char* p = (char*)d_ws;
  int*   odeg   = (int*)p;            p += (size_t)N * 4;
  int*   ideg   = (int*)p;            p += (size_t)N * 4;
  float* nout   = (float*)p;          p += (size_t)N * 4;
  float* nin    = (float*)p;          p += (size_t)N * 4;
  int*   rowptr = (int*)p;            p += ((size_t)N + 8) * 4;
  int*   cursor = (int*)p;            p += (size_t)N * 4;
  int*   bsums  = (int*)p;            p += 1024 * 4;
  int*   csr    = (int*)p;            p += (size_t)E * 4;
  p = (char*)(((uintptr_t)p + 15) & ~(uintptr_t)15);
  float* bufA   = (float*)p;          p += (size_t)N * 64 * 4;
  float* bufB   = (float*)p;          p += (size_t)N * 64 * 4;

  const int nb = (N + 255) / 256;

  // ---- degrees + norms ----
  hipMemsetAsync(odeg, 0, 2 * (size_t)N * sizeof(int), stream);  // odeg+ideg contiguous
  deg_kernel<<<(E + 255) / 256, 256, 0, stream>>>(src, dst, odeg, ideg, E);
  norm_kernel<<<nb, 256, 0, stream>>>(odeg, ideg, nout, nin, N);

  // ---- CSR build: rowptr = exclusive_scan(ideg); fill by dst ----
  scan1<<<nb, 256, 0, stream>>>(ideg, rowptr, bsums, N);
  scan_top<<<1, 256, 0, stream>>>(bsums, nb);
  add_off<<<nb, 256, 0, stream>>>(rowptr, bsums, N, E);
  hipMemsetAsync(cursor, 0, (size_t)N * sizeof(int), stream);
  fill_csr<<<(E + 255) / 256, 256, 0, stream>>>(src, dst, rowptr, cursor, csr, E);

  const int gemm_blocks = (N + 63) / 64;
  const int agg_blocks  = (N * 16 + 255) / 256;

  // ---- layer 1: bufA = (feat@W1)*nout; agg -> h1; out=h1; bufB = h1*nout ----
  gemm_kernel<128, false, false, true, true><<<gemm_blocks, 256, 0, stream>>>(
      feat, W1, nullptr, nullptr, nout, bufA, nullptr, N);
  agg_kernel<true><<<agg_blocks, 256, 0, stream>>>(rowptr, csr, bufA, nin, b1, nout, bufB, out, N);

  // ---- layer 2: bufA = agg(bufB); h2 = relu(nin*bufA@W2 + b2); out=max; bufB = h2*nout ----
  agg_kernel<false><<<agg_blocks, 256, 0, stream>>>(rowptr, csr, bufB, nullptr, nullptr, nullptr, bufA, nullptr, N);
  gemm_kernel<64, true, true, true, true><<<gemm_blocks, 256, 0, stream>>>(
      bufA, W2, nin, b2, nout, bufB, out, N);

  // ---- layer 3: bufA = agg(bufB); h3 = relu(nin*bufA@W3 + b3); out=max ----
  agg_kernel<false><<<agg_blocks, 256, 0, stream>>>(rowptr, csr, bufB, nullptr, nullptr, nullptr, bufA, nullptr, N);
  gemm_kernel<64, true, true, false, false><<<gemm_blocks, 256, 0, stream>>>(
      bufA, W3, nin, b3, nullptr, nullptr, out, N);
}

// Round 3
// 302.442 us; speedup vs baseline: 7.6376x; 1.0337x over previous
//
#include <hip/hip_runtime.h>

#define RANGES 4
#define PPR    32            // partial blocks per range
#define BINS   12544         // bins per range (>= ceil(50000/4)), multiple of 256
#define HWORDS (BINS)        // packed words per block partial: BINS/2 odeg + BINS/2 ideg

// ======== histogram: 16-bit-packed LDS counters, per-range partials ========
__global__ __launch_bounds__(256) void hist_kernel(const int* __restrict__ src,
                                                   const int* __restrict__ dst,
                                                   int* __restrict__ partial, int E) {
  __shared__ int h[HWORDS];  // 50 KB
  const int r = blockIdx.x >> 5;   // range (PPR=32)
  const int c = blockIdx.x & 31;   // chunk
  for (int i = threadIdx.x; i < HWORDS; i += 256) h[i] = 0;
  __syncthreads();
  const int lo = r * BINS;
  const int chunk = (E + PPR - 1) / PPR;
  const int e0 = c * chunk;
  const int e1 = min(E, e0 + chunk);
  for (int e = e0 + threadIdx.x; e < e1; e += 256) {
    int s = src[e] - lo;
    if ((unsigned)s < (unsigned)BINS) atomicAdd(&h[s >> 1], 1 << ((s & 1) * 16));
    int d = dst[e] - lo;
    if ((unsigned)d < (unsigned)BINS) atomicAdd(&h[(BINS / 2) + (d >> 1)], 1 << ((d & 1) * 16));
  }
  __syncthreads();
  int* op = partial + (size_t)blockIdx.x * HWORDS;
  for (int i = threadIdx.x; i < HWORDS; i += 256) op[i] = h[i];
}

// ======== fused: reduce partials -> degrees -> norms + first-level scan ========
__global__ __launch_bounds__(256) void reduce_norm_scan1(
    const int* __restrict__ partial, float* __restrict__ nout, float* __restrict__ nin,
    int* __restrict__ rowptr, int* __restrict__ bsums, int N) {
  __shared__ int s[256];
  const int i = blockIdx.x * 256 + threadIdx.x;   // node id (may be >= N)
  const int r = i / BINS;                         // uniform per block (BINS % 256 == 0)
  const int l = i % BINS;
  const int wo = l >> 1, sh = (l & 1) * 16;
  int sumO = 0, sumI = 0;
  const int* base = partial + (size_t)(r * PPR) * HWORDS;
#pragma unroll 4
  for (int p = 0; p < PPR; ++p) {
    sumO += base[(size_t)p * HWORDS + wo];
    sumI += base[(size_t)p * HWORDS + (BINS / 2) + wo];
  }
  const int od = (sumO >> sh) & 0xFFFF;           // halves can't carry: totals << 65536
  const int id = (sumI >> sh) & 0xFFFF;
  if (i < N) {
    nout[i] = od > 0 ? rsqrtf((float)od) : 0.f;
    nin[i]  = id > 0 ? rsqrtf((float)id) : 0.f;
  }
  const int v = (i < N) ? id : 0;
  s[threadIdx.x] = v;
  __syncthreads();
#pragma unroll
  for (int off = 1; off < 256; off <<= 1) {
    int tv = 0;
    if (threadIdx.x >= off) tv = s[threadIdx.x - off];
    __syncthreads();
    if (threadIdx.x >= off) s[threadIdx.x] += tv;
    __syncthreads();
  }
  if (i < N) rowptr[i] = s[threadIdx.x] - v;
  if (threadIdx.x == 255) bsums[blockIdx.x] = s[255];
}

__global__ void scan_top(int* __restrict__ bsums, int nb) {
  __shared__ int s[256];
  __shared__ int run_s;
  if (threadIdx.x == 0) run_s = 0;
  __syncthreads();
  for (int base = 0; base < nb; base += 256) {
    int i = base + threadIdx.x;
    int v = (i < nb) ? bsums[i] : 0;
    s[threadIdx.x] = v;
    __syncthreads();
#pragma unroll
    for (int off = 1; off < 256; off <<= 1) {
      int tv = 0;
      if (threadIdx.x >= off) tv = s[threadIdx.x - off];
      __syncthreads();
      if (threadIdx.x >= off) s[threadIdx.x] += tv;
      __syncthreads();
    }
    int run = run_s;
    if (i < nb) bsums[i] = run + s[threadIdx.x] - v;
    __syncthreads();
    if (threadIdx.x == 0) run_s = run + s[255];
    __syncthreads();
  }
}

// rowptr += block offset; cursor = final rowptr; rowptr[N] = E
__global__ void add_off(int* __restrict__ rowptr, int* __restrict__ cursor,
                        const int* __restrict__ bsums, int N, int E) {
  int i = blockIdx.x * 256 + threadIdx.x;
  if (i < N) {
    int v = rowptr[i] + bsums[blockIdx.x];
    rowptr[i] = v;
    cursor[i] = v;
  }
  if (blockIdx.x == 0 && threadIdx.x == 0) rowptr[N] = E;
}

// ======== CSR fill: absolute-position atomic cursor ========
__global__ void fill_csr(const int* __restrict__ src, const int* __restrict__ dst,
                         int* __restrict__ cursor, int* __restrict__ csr, int E) {
  int e = blockIdx.x * blockDim.x + threadIdx.x;
  if (e >= E) return;
  int pos = atomicAdd(&cursor[dst[e]], 1);
  csr[pos] = src[e];
}

// ======== gather aggregation (16 lanes / node, float4) ========
// x pre-scaled by nout[src] on the producer side.
// L1: out = relu(acc*nin + bias); y = out * nout.  else: y = raw acc
template <bool L1>
__global__ void agg_kernel(const int* __restrict__ rowptr, const int* __restrict__ csr,
                           const float* __restrict__ x, const float* __restrict__ nin,
                           const float* __restrict__ bias, const float* __restrict__ nout,
                           float* __restrict__ y, float* __restrict__ out, int N) {
  int t = blockIdx.x * blockDim.x + threadIdx.x;
  int node = t >> 4;
  if (node >= N) return;
  int lane = t & 15;
  int b = rowptr[node], e = rowptr[node + 1];
  float4 acc = make_float4(0.f, 0.f, 0.f, 0.f);
  for (int i = b; i < e; ++i) {
    int s = csr[i];
    float4 v = *reinterpret_cast<const float4*>(x + (size_t)s * 64 + lane * 4);
    acc.x += v.x; acc.y += v.y; acc.z += v.z; acc.w += v.w;
  }
  size_t off = (size_t)node * 64 + lane * 4;
  if (L1) {
    float s = nin[node];
    float4 bb = *reinterpret_cast<const float4*>(bias + lane * 4);
    float4 h;
    h.x = fmaxf(acc.x * s + bb.x, 0.f);
    h.y = fmaxf(acc.y * s + bb.y, 0.f);
    h.z = fmaxf(acc.z * s + bb.z, 0.f);
    h.w = fmaxf(acc.w * s + bb.w, 0.f);
    *reinterpret_cast<float4*>(out + off) = h;
    float no = nout[node];
    h.x *= no; h.y *= no; h.z *= no; h.w *= no;
    *reinterpret_cast<float4*>(y + off) = h;
  } else {
    *reinterpret_cast<float4*>(y + off) = acc;
  }
}

// ======== tiled GEMM: C[M x 64] = (INSCALE? diag(nin)*A : A)[M x K] @ B[K x 64] ========
// FUSED: h = relu(AB + bias); out = max(out, h); C = (OUTS? h*nout : h) if WRITEC
// !FUSED: C = (OUTS? v*nout : v)
template <int K, bool INSCALE, bool FUSED, bool OUTS, bool WRITEC>
__global__ __launch_bounds__(256) void gemm_kernel(
    const float* __restrict__ A, const float* __restrict__ B,
    const float* __restrict__ nin, const float* __restrict__ bias,
    const float* __restrict__ nout,
    float* __restrict__ C, float* __restrict__ out, int M) {
  __shared__ float sA[64][K + 4];
  __shared__ float sB[K][64];
  const int t = threadIdx.x;
  const int row0 = blockIdx.x * 64;

  for (int i = t * 4; i < 64 * K; i += 256 * 4) {
    int r = i / K, c = i % K;
    int gr = row0 + r;
    float4 v = make_float4(0.f, 0.f, 0.f, 0.f);
    if (gr < M) {
      v = *reinterpret_cast<const float4*>(A + (size_t)gr * K + c);
      if (INSCALE) {
        float s = nin[gr];
        v.x *= s; v.y *= s; v.z *= s; v.w *= s;
      }
    }
    *reinterpret_cast<float4*>(&sA[r][c]) = v;
  }
  for (int i = t * 4; i < K * 64; i += 256 * 4) {
    *reinterpret_cast<float4*>(&sB[0][0] + i) = *reinterpret_cast<const float4*>(B + i);
  }
  __syncthreads();

  const int ty = t >> 4;
  const int tx = t & 15;
  float acc[4][4] = {};
#pragma unroll 8
  for (int k = 0; k < K; ++k) {
    float a[4];
#pragma unroll
    for (int i = 0; i < 4; ++i) a[i] = sA[ty * 4 + i][k];
    float4 b = *reinterpret_cast<float4*>(&sB[k][tx * 4]);
#pragma unroll
    for (int i = 0; i < 4; ++i) {
      acc[i][0] += a[i] * b.x;
      acc[i][1] += a[i] * b.y;
      acc[i][2] += a[i] * b.z;
      acc[i][3] += a[i] * b.w;
    }
  }

#pragma unroll
  for (int i = 0; i < 4; ++i) {
    int gr = row0 + ty * 4 + i;
    if (gr >= M) continue;
    float4 v = make_float4(acc[i][0], acc[i][1], acc[i][2], acc[i][3]);
    size_t off = (size_t)gr * 64 + tx * 4;
    if (FUSED) {
      float4 b = *reinterpret_cast<const float4*>(bias + tx * 4);
      float4 h;
      h.x = fmaxf(v.x + b.x, 0.f);
      h.y = fmaxf(v.y + b.y, 0.f);
      h.z = fmaxf(v.z + b.z, 0.f);
      h.w = fmaxf(v.w + b.w, 0.f);
      float4 o = *reinterpret_cast<float4*>(out + off);
      o.x = fmaxf(o.x, h.x);
      o.y = fmaxf(o.y, h.y);
      o.z = fmaxf(o.z, h.z);
      o.w = fmaxf(o.w, h.w);
      *reinterpret_cast<float4*>(out + off) = o;
      if (WRITEC) {
        if (OUTS) {
          float no = nout[gr];
          h.x *= no; h.y *= no; h.z *= no; h.w *= no;
        }
        *reinterpret_cast<float4*>(C + off) = h;
      }
    } else {
      if (OUTS) {
        float no = nout[gr];
        v.x *= no; v.y *= no; v.z *= no; v.w *= no;
      }
      *reinterpret_cast<float4*>(C + off) = v;
    }
  }
}

extern "C" void kernel_launch(void* const* d_in, const int* in_sizes, int n_in,
                              void* d_out, int out_size, void* d_ws, size_t ws_size,
                              hipStream_t stream) {
  const float* feat = (const float*)d_in[0];
  const int* src    = (const int*)d_in[1];
  const int* dst    = (const int*)d_in[2];
  const float* W1   = (const float*)d_in[3];
  const float* b1   = (const float*)d_in[4];
  const float* W2   = (const float*)d_in[5];
  const float* b2   = (const float*)d_in[6];
  const float* W3   = (const float*)d_in[7];
  const float* b3   = (const float*)d_in[8];
  float* out = (float*)d_out;

  const int N = in_sizes[0] / 128;
  const int E = in_sizes[1];

  // ---- workspace layout ----
  char* p = (char*)d_ws;
  float* nout   = (float*)p;          p += (size_t)N * 4;
  float* nin    = (float*)p;          p += (size_t)N * 4;
  int*   rowptr = (int*)p;            p += ((size_t)N + 8) * 4;
  int*   cursor = (int*)p;            p += (size_t)N * 4;
  int*   bsums  = (int*)p;            p += 1024 * 4;
  int*   csr    = (int*)p;            p += (size_t)E * 4;
  p = (char*)(((uintptr_t)p + 15) & ~(uintptr_t)15);
  float* bufA   = (float*)p;          p += (size_t)N * 64 * 4;
  float* bufB   = (float*)p;          p += (size_t)N * 64 * 4;
  int*   partial = (int*)bufB;        // RANGES*PPR*HWORDS*4 = 6.4 MB <= bufB (dead until agg1)

  const int nbins_total = RANGES * BINS;          // 50176 >= N
  const int nb = nbins_total / 256;               // 196 scan blocks

  // ---- degrees + norms + rowptr (histogram path) ----
  hist_kernel<<<RANGES * PPR, 256, 0, stream>>>(src, dst, partial, E);
  reduce_norm_scan1<<<nb, 256, 0, stream>>>(partial, nout, nin, rowptr, bsums, N);
  scan_top<<<1, 256, 0, stream>>>(bsums, nb);
  add_off<<<nb, 256, 0, stream>>>(rowptr, cursor, bsums, N, E);
  fill_csr<<<(E + 255) / 256, 256, 0, stream>>>(src, dst, cursor, csr, E);

  const int gemm_blocks = (N + 63) / 64;
  const int agg_blocks  = (N * 16 + 255) / 256;

  // ---- layer 1: bufA = (feat@W1)*nout; agg -> out=h1; bufB = h1*nout ----
  gemm_kernel<128, false, false, true, true><<<gemm_blocks, 256, 0, stream>>>(
      feat, W1, nullptr, nullptr, nout, bufA, nullptr, N);
  agg_kernel<true><<<agg_blocks, 256, 0, stream>>>(rowptr, csr, bufA, nin, b1, nout, bufB, out, N);

  // ---- layer 2: bufA = agg(bufB); h2 = relu(nin*bufA@W2 + b2); out=max; bufB = h2*nout ----
  agg_kernel<false><<<agg_blocks, 256, 0, stream>>>(rowptr, csr, bufB, nullptr, nullptr, nullptr, bufA, nullptr, N);
  gemm_kernel<64, true, true, true, true><<<gemm_blocks, 256, 0, stream>>>(
      bufA, W2, nin, b2, nout, bufB, out, N);

  // ---- layer 3: bufA = agg(bufB); h3 = relu(nin*bufA@W3 + b3); out=max ----
  agg_kernel<false><<<agg_blocks, 256, 0, stream>>>(rowptr, csr, bufB, nullptr, nullptr, nullptr, bufA, nullptr, N);
  gemm_kernel<64, true, true, false, false><<<gemm_blocks, 256, 0, stream>>>(
      bufA, W3, nin, b3, nullptr, nullptr, out, N);
}

// Round 4
// 260.231 us; speedup vs baseline: 8.8765x; 1.1622x over previous
//
#include <hip/hip_runtime.h>

#define RANGES 4
#define PPR    64            // partial blocks (chunks) per range
#define HTHREADS 1024
#define BINS   12544         // bins per range (>= ceil(50000/4)), multiple of 256
#define HWORDS (BINS)        // packed words per partial: BINS/2 odeg + BINS/2 ideg

// ======== histogram: 16-bit-packed LDS counters, per-range partials ========
__global__ __launch_bounds__(HTHREADS) void hist_kernel(const int* __restrict__ src,
                                                        const int* __restrict__ dst,
                                                        int* __restrict__ partial, int E) {
  __shared__ int h[HWORDS];  // 50 KB
  const int r = blockIdx.x >> 6;   // range (PPR=64)
  const int c = blockIdx.x & 63;   // chunk
  for (int i = threadIdx.x; i < HWORDS; i += HTHREADS) h[i] = 0;
  __syncthreads();
  const int lo = r * BINS;
  const int chunk = (E + PPR - 1) / PPR;
  const int e0 = c * chunk;
  const int e1 = min(E, e0 + chunk);
  for (int e = e0 + threadIdx.x; e < e1; e += HTHREADS) {
    int s = src[e] - lo;
    if ((unsigned)s < (unsigned)BINS) atomicAdd(&h[s >> 1], 1 << ((s & 1) * 16));
    int d = dst[e] - lo;
    if ((unsigned)d < (unsigned)BINS) atomicAdd(&h[(BINS / 2) + (d >> 1)], 1 << ((d & 1) * 16));
  }
  __syncthreads();
  int* op = partial + (size_t)blockIdx.x * HWORDS;
  for (int i = threadIdx.x; i < HWORDS; i += HTHREADS) op[i] = h[i];
}

// ======== fused: reduce partials -> degrees -> norms + first-level scan ========
__global__ __launch_bounds__(256) void reduce_norm_scan1(
    const int* __restrict__ partial, float* __restrict__ nout, float* __restrict__ nin,
    int* __restrict__ rowptr, int* __restrict__ bsums, int N) {
  __shared__ int s[256];
  const int i = blockIdx.x * 256 + threadIdx.x;   // node id (may be >= N)
  const int r = i / BINS;                         // uniform per block (BINS % 256 == 0)
  const int l = i % BINS;
  const int wo = l >> 1, sh = (l & 1) * 16;
  int sumO = 0, sumI = 0;
  const int* base = partial + (size_t)(r * PPR) * HWORDS;
#pragma unroll 8
  for (int p = 0; p < PPR; ++p) {
    sumO += base[(size_t)p * HWORDS + wo];
    sumI += base[(size_t)p * HWORDS + (BINS / 2) + wo];
  }
  const int od = (sumO >> sh) & 0xFFFF;           // halves can't carry: totals << 65536
  const int id = (sumI >> sh) & 0xFFFF;
  if (i < N) {
    nout[i] = od > 0 ? rsqrtf((float)od) : 0.f;
    nin[i]  = id > 0 ? rsqrtf((float)id) : 0.f;
  }
  const int v = (i < N) ? id : 0;
  s[threadIdx.x] = v;
  __syncthreads();
#pragma unroll
  for (int off = 1; off < 256; off <<= 1) {
    int tv = 0;
    if (threadIdx.x >= off) tv = s[threadIdx.x - off];
    __syncthreads();
    if (threadIdx.x >= off) s[threadIdx.x] += tv;
    __syncthreads();
  }
  if (i < N) rowptr[i] = s[threadIdx.x] - v;
  if (threadIdx.x == 255) bsums[blockIdx.x] = s[255];
}

__global__ void scan_top(int* __restrict__ bsums, int nb) {
  __shared__ int s[256];
  __shared__ int run_s;
  if (threadIdx.x == 0) run_s = 0;
  __syncthreads();
  for (int base = 0; base < nb; base += 256) {
    int i = base + threadIdx.x;
    int v = (i < nb) ? bsums[i] : 0;
    s[threadIdx.x] = v;
    __syncthreads();
#pragma unroll
    for (int off = 1; off < 256; off <<= 1) {
      int tv = 0;
      if (threadIdx.x >= off) tv = s[threadIdx.x - off];
      __syncthreads();
      if (threadIdx.x >= off) s[threadIdx.x] += tv;
      __syncthreads();
    }
    int run = run_s;
    if (i < nb) bsums[i] = run + s[threadIdx.x] - v;
    __syncthreads();
    if (threadIdx.x == 0) run_s = run + s[255];
    __syncthreads();
  }
}

// rowptr += block offset; cursor = final rowptr; rowptr[N] = E
__global__ void add_off(int* __restrict__ rowptr, int* __restrict__ cursor,
                        const int* __restrict__ bsums, int N, int E) {
  int i = blockIdx.x * 256 + threadIdx.x;
  if (i < N) {
    int v = rowptr[i] + bsums[blockIdx.x];
    rowptr[i] = v;
    cursor[i] = v;
  }
  if (blockIdx.x == 0 && threadIdx.x == 0) rowptr[N] = E;
}

// ======== CSR fill: absolute-position atomic cursor ========
__global__ void fill_csr(const int* __restrict__ src, const int* __restrict__ dst,
                         int* __restrict__ cursor, int* __restrict__ csr, int E) {
  int e = blockIdx.x * blockDim.x + threadIdx.x;
  if (e >= E) return;
  int pos = atomicAdd(&cursor[dst[e]], 1);
  csr[pos] = src[e];
}

// ======== gather aggregation (16 lanes / node, float4) ========
// x pre-scaled by nout[src] on the producer side.
// L1: out = relu(acc*nin + bias); y = out * nout.  else: y = raw acc
template <bool L1>
__global__ void agg_kernel(const int* __restrict__ rowptr, const int* __restrict__ csr,
                           const float* __restrict__ x, const float* __restrict__ nin,
                           const float* __restrict__ bias, const float* __restrict__ nout,
                           float* __restrict__ y, float* __restrict__ out, int N) {
  int t = blockIdx.x * blockDim.x + threadIdx.x;
  int node = t >> 4;
  if (node >= N) return;
  int lane = t & 15;
  int b = rowptr[node], e = rowptr[node + 1];
  float4 acc = make_float4(0.f, 0.f, 0.f, 0.f);
  for (int i = b; i < e; ++i) {
    int s = csr[i];
    float4 v = *reinterpret_cast<const float4*>(x + (size_t)s * 64 + lane * 4);
    acc.x += v.x; acc.y += v.y; acc.z += v.z; acc.w += v.w;
  }
  size_t off = (size_t)node * 64 + lane * 4;
  if (L1) {
    float s = nin[node];
    float4 bb = *reinterpret_cast<const float4*>(bias + lane * 4);
    float4 h;
    h.x = fmaxf(acc.x * s + bb.x, 0.f);
    h.y = fmaxf(acc.y * s + bb.y, 0.f);
    h.z = fmaxf(acc.z * s + bb.z, 0.f);
    h.w = fmaxf(acc.w * s + bb.w, 0.f);
    *reinterpret_cast<float4*>(out + off) = h;
    float no = nout[node];
    h.x *= no; h.y *= no; h.z *= no; h.w *= no;
    *reinterpret_cast<float4*>(y + off) = h;
  } else {
    *reinterpret_cast<float4*>(y + off) = acc;
  }
}

// ======== tiled GEMM: C[M x 64] = (INSCALE? diag(nin)*A : A)[M x K] @ B[K x 64] ========
// FUSED: h = relu(AB + bias); out = max(out, h); C = (OUTS? h*nout : h) if WRITEC
// !FUSED: C = (OUTS? v*nout : v)
template <int K, bool INSCALE, bool FUSED, bool OUTS, bool WRITEC>
__global__ __launch_bounds__(256) void gemm_kernel(
    const float* __restrict__ A, const float* __restrict__ B,
    const float* __restrict__ nin, const float* __restrict__ bias,
    const float* __restrict__ nout,
    float* __restrict__ C, float* __restrict__ out, int M) {
  __shared__ float sA[64][K + 4];
  __shared__ float sB[K][64];
  const int t = threadIdx.x;
  const int row0 = blockIdx.x * 64;

  for (int i = t * 4; i < 64 * K; i += 256 * 4) {
    int r = i / K, c = i % K;
    int gr = row0 + r;
    float4 v = make_float4(0.f, 0.f, 0.f, 0.f);
    if (gr < M) {
      v = *reinterpret_cast<const float4*>(A + (size_t)gr * K + c);
      if (INSCALE) {
        float s = nin[gr];
        v.x *= s; v.y *= s; v.z *= s; v.w *= s;
      }
    }
    *reinterpret_cast<float4*>(&sA[r][c]) = v;
  }
  for (int i = t * 4; i < K * 64; i += 256 * 4) {
    *reinterpret_cast<float4*>(&sB[0][0] + i) = *reinterpret_cast<const float4*>(B + i);
  }
  __syncthreads();

  const int ty = t >> 4;
  const int tx = t & 15;
  float acc[4][4] = {};
#pragma unroll 8
  for (int k = 0; k < K; ++k) {
    float a[4];
#pragma unroll
    for (int i = 0; i < 4; ++i) a[i] = sA[ty * 4 + i][k];
    float4 b = *reinterpret_cast<float4*>(&sB[k][tx * 4]);
#pragma unroll
    for (int i = 0; i < 4; ++i) {
      acc[i][0] += a[i] * b.x;
      acc[i][1] += a[i] * b.y;
      acc[i][2] += a[i] * b.z;
      acc[i][3] += a[i] * b.w;
    }
  }

#pragma unroll
  for (int i = 0; i < 4; ++i) {
    int gr = row0 + ty * 4 + i;
    if (gr >= M) continue;
    float4 v = make_float4(acc[i][0], acc[i][1], acc[i][2], acc[i][3]);
    size_t off = (size_t)gr * 64 + tx * 4;
    if (FUSED) {
      float4 b = *reinterpret_cast<const float4*>(bias + tx * 4);
      float4 h;
      h.x = fmaxf(v.x + b.x, 0.f);
      h.y = fmaxf(v.y + b.y, 0.f);
      h.z = fmaxf(v.z + b.z, 0.f);
      h.w = fmaxf(v.w + b.w, 0.f);
      float4 o = *reinterpret_cast<float4*>(out + off);
      o.x = fmaxf(o.x, h.x);
      o.y = fmaxf(o.y, h.y);
      o.z = fmaxf(o.z, h.z);
      o.w = fmaxf(o.w, h.w);
      *reinterpret_cast<float4*>(out + off) = o;
      if (WRITEC) {
        if (OUTS) {
          float no = nout[gr];
          h.x *= no; h.y *= no; h.z *= no; h.w *= no;
        }
        *reinterpret_cast<float4*>(C + off) = h;
      }
    } else {
      if (OUTS) {
        float no = nout[gr];
        v.x *= no; v.y *= no; v.z *= no; v.w *= no;
      }
      *reinterpret_cast<float4*>(C + off) = v;
    }
  }
}

extern "C" void kernel_launch(void* const* d_in, const int* in_sizes, int n_in,
                              void* d_out, int out_size, void* d_ws, size_t ws_size,
                              hipStream_t stream) {
  const float* feat = (const float*)d_in[0];
  const int* src    = (const int*)d_in[1];
  const int* dst    = (const int*)d_in[2];
  const float* W1   = (const float*)d_in[3];
  const float* b1   = (const float*)d_in[4];
  const float* W2   = (const float*)d_in[5];
  const float* b2   = (const float*)d_in[6];
  const float* W3   = (const float*)d_in[7];
  const float* b3   = (const float*)d_in[8];
  float* out = (float*)d_out;

  const int N = in_sizes[0] / 128;
  const int E = in_sizes[1];

  // ---- workspace layout ----
  char* p = (char*)d_ws;
  float* nout   = (float*)p;          p += (size_t)N * 4;
  float* nin    = (float*)p;          p += (size_t)N * 4;
  int*   rowptr = (int*)p;            p += ((size_t)N + 8) * 4;
  int*   cursor = (int*)p;            p += (size_t)N * 4;
  int*   bsums  = (int*)p;            p += 1024 * 4;
  int*   csr    = (int*)p;            p += (size_t)E * 4;
  p = (char*)(((uintptr_t)p + 15) & ~(uintptr_t)15);
  float* bufA   = (float*)p;          p += (size_t)N * 64 * 4;
  float* bufB   = (float*)p;          p += (size_t)N * 64 * 4;
  // partial = RANGES*PPR*HWORDS*4 = 12.85 MB, aliased over bufA (+45 KB into bufB).
  // Dead after reduce_norm_scan1, which completes before gemm1 writes bufA (same stream).
  int*   partial = (int*)bufA;

  const int nbins_total = RANGES * BINS;          // 50176 >= N
  const int nb = nbins_total / 256;               // 196 scan blocks

  // ---- degrees + norms + rowptr (histogram path) ----
  hist_kernel<<<RANGES * PPR, HTHREADS, 0, stream>>>(src, dst, partial, E);
  reduce_norm_scan1<<<nb, 256, 0, stream>>>(partial, nout, nin, rowptr, bsums, N);
  scan_top<<<1, 256, 0, stream>>>(bsums, nb);
  add_off<<<nb, 256, 0, stream>>>(rowptr, cursor, bsums, N, E);
  fill_csr<<<(E + 255) / 256, 256, 0, stream>>>(src, dst, cursor, csr, E);

  const int gemm_blocks = (N + 63) / 64;
  const int agg_blocks  = (N * 16 + 255) / 256;

  // ---- layer 1: bufA = (feat@W1)*nout; agg -> out=h1; bufB = h1*nout ----
  gemm_kernel<128, false, false, true, true><<<gemm_blocks, 256, 0, stream>>>(
      feat, W1, nullptr, nullptr, nout, bufA, nullptr, N);
  agg_kernel<true><<<agg_blocks, 256, 0, stream>>>(rowptr, csr, bufA, nin, b1, nout, bufB, out, N);

  // ---- layer 2: bufA = agg(bufB); h2 = relu(nin*bufA@W2 + b2); out=max; bufB = h2*nout ----
  agg_kernel<false><<<agg_blocks, 256, 0, stream>>>(rowptr, csr, bufB, nullptr, nullptr, nullptr, bufA, nullptr, N);
  gemm_kernel<64, true, true, true, true><<<gemm_blocks, 256, 0, stream>>>(
      bufA, W2, nin, b2, nout, bufB, out, N);

  // ---- layer 3: bufA = agg(bufB); h3 = relu(nin*bufA@W3 + b3); out=max ----
  agg_kernel<false><<<agg_blocks, 256, 0, stream>>>(rowptr, csr, bufB, nullptr, nullptr, nullptr, bufA, nullptr, N);
  gemm_kernel<64, true, true, false, false><<<gemm_blocks, 256, 0, stream>>>(
      bufA, W3, nin, b3, nullptr, nullptr, out, N);
}

// Round 5
// 236.108 us; speedup vs baseline: 9.7834x; 1.1022x over previous
//
#include <hip/hip_runtime.h>

#define RANGES 8
#define PPR    32            // chunks (partials per range)
#define HTHREADS 1024
#define BINS   6400          // nodes per range: 8*6400 = 51200 >= 50000; 6400 % 256 == 0
#define HALF   (BINS / 2)    // packed words per histogram (odeg or ideg)
#define HWORDS (BINS)        // words per partial block: HALF odeg + HALF ideg

// ======== histogram: 16-bit-packed LDS counters, per-(range,chunk) partials ========
__global__ __launch_bounds__(HTHREADS) void hist_kernel(const int* __restrict__ src,
                                                        const int* __restrict__ dst,
                                                        int* __restrict__ partial, int E) {
  __shared__ int h[HWORDS];  // 25.6 KB
  const int r = blockIdx.x >> 5;   // range
  const int c = blockIdx.x & 31;   // chunk
  for (int i = threadIdx.x; i < HWORDS; i += HTHREADS) h[i] = 0;
  __syncthreads();
  const int lo = r * BINS;
  const int chunk = (E + PPR - 1) / PPR;
  const int e0 = c * chunk;
  const int e1 = min(E, e0 + chunk);
  for (int e = e0 + threadIdx.x; e < e1; e += HTHREADS) {
    int s = src[e] - lo;
    if ((unsigned)s < (unsigned)BINS) atomicAdd(&h[s >> 1], 1 << ((s & 1) * 16));
    int d = dst[e] - lo;
    if ((unsigned)d < (unsigned)BINS) atomicAdd(&h[HALF + (d >> 1)], 1 << ((d & 1) * 16));
  }
  __syncthreads();
  int* op = partial + (size_t)blockIdx.x * HWORDS;
  for (int i = threadIdx.x; i < HWORDS; i += HTHREADS) op[i] = h[i];
}

// ======== fused: reduce partials -> norms; in-place chunk-prefix; first-level scan ========
// One thread per packed WORD (2 nodes). word j -> nodes 2j, 2j+1.
__global__ __launch_bounds__(256) void reduce_norm_scan1(
    int* __restrict__ partial, float* __restrict__ nout, float* __restrict__ nin,
    int* __restrict__ rowptr, int* __restrict__ bsums, int N) {
  __shared__ int s[256];
  const int j = blockIdx.x * 256 + threadIdx.x;    // packed word id, < RANGES*HALF
  const int r = j / HALF;
  const int w = j % HALF;
  int* base = partial + (size_t)(r * PPR) * HWORDS;
  int sumO = 0, runI = 0;
#pragma unroll 8
  for (int p = 0; p < PPR; ++p) {
    sumO += base[(size_t)p * HWORDS + w];
    int vI = base[(size_t)p * HWORDS + HALF + w];
    base[(size_t)p * HWORDS + HALF + w] = runI;    // exclusive chunk-prefix (packed; no carry)
    runI += vI;
  }
  const int od0 = sumO & 0xFFFF, od1 = (sumO >> 16) & 0xFFFF;
  const int id0 = runI & 0xFFFF, id1 = (runI >> 16) & 0xFFFF;
  const int n0 = 2 * j, n1 = 2 * j + 1;
  if (n0 < N) {
    nout[n0] = od0 > 0 ? rsqrtf((float)od0) : 0.f;
    nin[n0]  = id0 > 0 ? rsqrtf((float)id0) : 0.f;
  }
  if (n1 < N) {
    nout[n1] = od1 > 0 ? rsqrtf((float)od1) : 0.f;
    nin[n1]  = id1 > 0 ? rsqrtf((float)id1) : 0.f;
  }
  // first-level exclusive scan of ideg (2 nodes per thread)
  const int local = id0 + id1;                      // 0 for nodes >= N (bins empty)
  int v = local;
  s[threadIdx.x] = v;
  __syncthreads();
#pragma unroll
  for (int off = 1; off < 256; off <<= 1) {
    int tv = 0;
    if (threadIdx.x >= off) tv = s[threadIdx.x - off];
    __syncthreads();
    if (threadIdx.x >= off) s[threadIdx.x] += tv;
    __syncthreads();
  }
  const int excl = s[threadIdx.x] - v;              // block-local exclusive start for node n0
  if (n0 < N) rowptr[n0] = excl;
  if (n1 < N) rowptr[n1] = excl + id0;
  if (threadIdx.x == 255) bsums[blockIdx.x] = s[255];
}

__global__ void scan_top(int* __restrict__ bsums, int nb) {
  __shared__ int s[256];
  __shared__ int run_s;
  if (threadIdx.x == 0) run_s = 0;
  __syncthreads();
  for (int base = 0; base < nb; base += 256) {
    int i = base + threadIdx.x;
    int v = (i < nb) ? bsums[i] : 0;
    s[threadIdx.x] = v;
    __syncthreads();
#pragma unroll
    for (int off = 1; off < 256; off <<= 1) {
      int tv = 0;
      if (threadIdx.x >= off) tv = s[threadIdx.x - off];
      __syncthreads();
      if (threadIdx.x >= off) s[threadIdx.x] += tv;
      __syncthreads();
    }
    int run = run_s;
    if (i < nb) bsums[i] = run + s[threadIdx.x] - v;
    __syncthreads();
    if (threadIdx.x == 0) run_s = run + s[255];
    __syncthreads();
  }
}

// rowptr += block offset (each scan block covered 512 nodes); rowptr[N] = E
__global__ void add_off(int* __restrict__ rowptr, const int* __restrict__ bsums, int N, int E) {
  int i = blockIdx.x * 512 + threadIdx.x;           // 512 threads/block
  if (i < N) rowptr[i] += bsums[blockIdx.x];
  if (blockIdx.x == 0 && threadIdx.x == 0) rowptr[N] = E;
}

// ======== CSR fill: LDS cursors, no global atomics; range = bid&7 for XCD L2 affinity ========
__global__ __launch_bounds__(HTHREADS) void fill_kernel(
    const int* __restrict__ src, const int* __restrict__ dst,
    const int* __restrict__ rowptr, const int* __restrict__ partial,
    int* __restrict__ csr, int N, int E) {
  __shared__ int cur[BINS];  // 25.6 KB absolute cursors
  const int r = blockIdx.x & 7;    // range -> XCD (empirical bid%8 round-robin)
  const int c = blockIdx.x >> 3;   // chunk
  const int lo = r * BINS;
  const int* pf = partial + (size_t)(r * PPR + c) * HWORDS + HALF;
  for (int n = threadIdx.x; n < BINS; n += HTHREADS) {
    int g = lo + n;
    int rp = (g < N) ? rowptr[g] : 0;
    int pw = pf[n >> 1];
    cur[n] = rp + ((pw >> ((n & 1) * 16)) & 0xFFFF);
  }
  __syncthreads();
  const int chunk = (E + PPR - 1) / PPR;
  const int e0 = c * chunk;
  const int e1 = min(E, e0 + chunk);
  for (int e = e0 + threadIdx.x; e < e1; e += HTHREADS) {
    int d = dst[e] - lo;
    if ((unsigned)d < (unsigned)BINS) {
      int pos = atomicAdd(&cur[d], 1);
      csr[pos] = src[e];
    }
  }
}

// ======== gather aggregation (16 lanes / node, float4) ========
// x pre-scaled by nout[src] on the producer side.
// L1: out = relu(acc*nin + bias); y = out * nout.  else: y = raw acc
template <bool L1>
__global__ void agg_kernel(const int* __restrict__ rowptr, const int* __restrict__ csr,
                           const float* __restrict__ x, const float* __restrict__ nin,
                           const float* __restrict__ bias, const float* __restrict__ nout,
                           float* __restrict__ y, float* __restrict__ out, int N) {
  int t = blockIdx.x * blockDim.x + threadIdx.x;
  int node = t >> 4;
  if (node >= N) return;
  int lane = t & 15;
  int b = rowptr[node], e = rowptr[node + 1];
  float4 acc = make_float4(0.f, 0.f, 0.f, 0.f);
  for (int i = b; i < e; ++i) {
    int s = csr[i];
    float4 v = *reinterpret_cast<const float4*>(x + (size_t)s * 64 + lane * 4);
    acc.x += v.x; acc.y += v.y; acc.z += v.z; acc.w += v.w;
  }
  size_t off = (size_t)node * 64 + lane * 4;
  if (L1) {
    float s = nin[node];
    float4 bb = *reinterpret_cast<const float4*>(bias + lane * 4);
    float4 h;
    h.x = fmaxf(acc.x * s + bb.x, 0.f);
    h.y = fmaxf(acc.y * s + bb.y, 0.f);
    h.z = fmaxf(acc.z * s + bb.z, 0.f);
    h.w = fmaxf(acc.w * s + bb.w, 0.f);
    *reinterpret_cast<float4*>(out + off) = h;
    float no = nout[node];
    h.x *= no; h.y *= no; h.z *= no; h.w *= no;
    *reinterpret_cast<float4*>(y + off) = h;
  } else {
    *reinterpret_cast<float4*>(y + off) = acc;
  }
}

// ======== tiled GEMM: C[M x 64] = (INSCALE? diag(nin)*A : A)[M x K] @ B[K x 64] ========
// FUSED: h = relu(AB + bias); out = max(out, h); C = (OUTS? h*nout : h) if WRITEC
// !FUSED: C = (OUTS? v*nout : v)
template <int K, bool INSCALE, bool FUSED, bool OUTS, bool WRITEC>
__global__ __launch_bounds__(256) void gemm_kernel(
    const float* __restrict__ A, const float* __restrict__ B,
    const float* __restrict__ nin, const float* __restrict__ bias,
    const float* __restrict__ nout,
    float* __restrict__ C, float* __restrict__ out, int M) {
  __shared__ float sA[64][K + 4];
  __shared__ float sB[K][64];
  const int t = threadIdx.x;
  const int row0 = blockIdx.x * 64;

  for (int i = t * 4; i < 64 * K; i += 256 * 4) {
    int r = i / K, c = i % K;
    int gr = row0 + r;
    float4 v = make_float4(0.f, 0.f, 0.f, 0.f);
    if (gr < M) {
      v = *reinterpret_cast<const float4*>(A + (size_t)gr * K + c);
      if (INSCALE) {
        float s = nin[gr];
        v.x *= s; v.y *= s; v.z *= s; v.w *= s;
      }
    }
    *reinterpret_cast<float4*>(&sA[r][c]) = v;
  }
  for (int i = t * 4; i < K * 64; i += 256 * 4) {
    *reinterpret_cast<float4*>(&sB[0][0] + i) = *reinterpret_cast<const float4*>(B + i);
  }
  __syncthreads();

  const int ty = t >> 4;
  const int tx = t & 15;
  float acc[4][4] = {};
#pragma unroll 8
  for (int k = 0; k < K; ++k) {
    float a[4];
#pragma unroll
    for (int i = 0; i < 4; ++i) a[i] = sA[ty * 4 + i][k];
    float4 b = *reinterpret_cast<float4*>(&sB[k][tx * 4]);
#pragma unroll
    for (int i = 0; i < 4; ++i) {
      acc[i][0] += a[i] * b.x;
      acc[i][1] += a[i] * b.y;
      acc[i][2] += a[i] * b.z;
      acc[i][3] += a[i] * b.w;
    }
  }

#pragma unroll
  for (int i = 0; i < 4; ++i) {
    int gr = row0 + ty * 4 + i;
    if (gr >= M) continue;
    float4 v = make_float4(acc[i][0], acc[i][1], acc[i][2], acc[i][3]);
    size_t off = (size_t)gr * 64 + tx * 4;
    if (FUSED) {
      float4 b = *reinterpret_cast<const float4*>(bias + tx * 4);
      float4 h;
      h.x = fmaxf(v.x + b.x, 0.f);
      h.y = fmaxf(v.y + b.y, 0.f);
      h.z = fmaxf(v.z + b.z, 0.f);
      h.w = fmaxf(v.w + b.w, 0.f);
      float4 o = *reinterpret_cast<float4*>(out + off);
      o.x = fmaxf(o.x, h.x);
      o.y = fmaxf(o.y, h.y);
      o.z = fmaxf(o.z, h.z);
      o.w = fmaxf(o.w, h.w);
      *reinterpret_cast<float4*>(out + off) = o;
      if (WRITEC) {
        if (OUTS) {
          float no = nout[gr];
          h.x *= no; h.y *= no; h.z *= no; h.w *= no;
        }
        *reinterpret_cast<float4*>(C + off) = h;
      }
    } else {
      if (OUTS) {
        float no = nout[gr];
        v.x *= no; v.y *= no; v.z *= no; v.w *= no;
      }
      *reinterpret_cast<float4*>(C + off) = v;
    }
  }
}

extern "C" void kernel_launch(void* const* d_in, const int* in_sizes, int n_in,
                              void* d_out, int out_size, void* d_ws, size_t ws_size,
                              hipStream_t stream) {
  const float* feat = (const float*)d_in[0];
  const int* src    = (const int*)d_in[1];
  const int* dst    = (const int*)d_in[2];
  const float* W1   = (const float*)d_in[3];
  const float* b1   = (const float*)d_in[4];
  const float* W2   = (const float*)d_in[5];
  const float* b2   = (const float*)d_in[6];
  const float* W3   = (const float*)d_in[7];
  const float* b3   = (const float*)d_in[8];
  float* out = (float*)d_out;

  const int N = in_sizes[0] / 128;
  const int E = in_sizes[1];

  // ---- workspace layout ----
  char* p = (char*)d_ws;
  float* nout   = (float*)p;          p += (size_t)N * 4;
  float* nin    = (float*)p;          p += (size_t)N * 4;
  int*   rowptr = (int*)p;            p += ((size_t)N + 8) * 4;
  int*   bsums  = (int*)p;            p += 1024 * 4;
  int*   csr    = (int*)p;            p += (size_t)E * 4;
  p = (char*)(((uintptr_t)p + 15) & ~(uintptr_t)15);
  float* bufA   = (float*)p;          p += (size_t)N * 64 * 4;
  float* bufB   = (float*)p;          p += (size_t)N * 64 * 4;
  // partial = RANGES*PPR*HWORDS*4 = 6.55 MB, aliased over bufA (12.8 MB).
  // Dead after fill_kernel, which completes before gemm1 writes bufA (same stream).
  int*   partial = (int*)bufA;

  const int nwords = RANGES * HALF;               // 25600 packed words
  const int nb = nwords / 256;                    // 100 scan blocks (512 nodes each)

  // ---- degrees + norms + rowptr + CSR (histogram path, no global atomics) ----
  hist_kernel<<<RANGES * PPR, HTHREADS, 0, stream>>>(src, dst, partial, E);
  reduce_norm_scan1<<<nb, 256, 0, stream>>>(partial, nout, nin, rowptr, bsums, N);
  scan_top<<<1, 256, 0, stream>>>(bsums, nb);
  add_off<<<nb, 512, 0, stream>>>(rowptr, bsums, N, E);
  fill_kernel<<<RANGES * PPR, HTHREADS, 0, stream>>>(src, dst, rowptr, partial, csr, N, E);

  const int gemm_blocks = (N + 63) / 64;
  const int agg_blocks  = (N * 16 + 255) / 256;

  // ---- layer 1: bufA = (feat@W1)*nout; agg -> out=h1; bufB = h1*nout ----
  gemm_kernel<128, false, false, true, true><<<gemm_blocks, 256, 0, stream>>>(
      feat, W1, nullptr, nullptr, nout, bufA, nullptr, N);
  agg_kernel<true><<<agg_blocks, 256, 0, stream>>>(rowptr, csr, bufA, nin, b1, nout, bufB, out, N);

  // ---- layer 2: bufA = agg(bufB); h2 = relu(nin*bufA@W2 + b2); out=max; bufB = h2*nout ----
  agg_kernel<false><<<agg_blocks, 256, 0, stream>>>(rowptr, csr, bufB, nullptr, nullptr, nullptr, bufA, nullptr, N);
  gemm_kernel<64, true, true, true, true><<<gemm_blocks, 256, 0, stream>>>(
      bufA, W2, nin, b2, nout, bufB, out, N);

  // ---- layer 3: bufA = agg(bufB); h3 = relu(nin*bufA@W3 + b3); out=max ----
  agg_kernel<false><<<agg_blocks, 256, 0, stream>>>(rowptr, csr, bufB, nullptr, nullptr, nullptr, bufA, nullptr, N);
  gemm_kernel<64, true, true, false, false><<<gemm_blocks, 256, 0, stream>>>(
      bufA, W3, nin, b3, nullptr, nullptr, out, N);
}

// Round 6
// 216.770 us; speedup vs baseline: 10.6562x; 1.0892x over previous
//
#include <hip/hip_runtime.h>

#define RANGES 8
#define PPR    32            // chunks (partials per range)
#define HTHREADS 1024
#define BINS   6400          // nodes per range: 8*6400 = 51200 >= 50000; 6400 % 256 == 0
#define HALF   (BINS / 2)    // packed words per histogram (odeg or ideg)
#define HWORDS (BINS)        // words per partial block: HALF odeg + HALF ideg

// ======== histogram: 16-bit-packed LDS counters, per-(range,chunk) partials ========
__global__ __launch_bounds__(HTHREADS) void hist_kernel(const int* __restrict__ src,
                                                        const int* __restrict__ dst,
                                                        int* __restrict__ partial, int E) {
  __shared__ int h[HWORDS];  // 25.6 KB
  const int r = blockIdx.x >> 5;   // range
  const int c = blockIdx.x & 31;   // chunk
  for (int i = threadIdx.x; i < HWORDS; i += HTHREADS) h[i] = 0;
  __syncthreads();
  const int lo = r * BINS;
  const int chunk = (E + PPR - 1) / PPR;
  const int e0 = c * chunk;
  const int e1 = min(E, e0 + chunk);
  for (int e = e0 + threadIdx.x; e < e1; e += HTHREADS) {
    int s = src[e] - lo;
    if ((unsigned)s < (unsigned)BINS) atomicAdd(&h[s >> 1], 1 << ((s & 1) * 16));
    int d = dst[e] - lo;
    if ((unsigned)d < (unsigned)BINS) atomicAdd(&h[HALF + (d >> 1)], 1 << ((d & 1) * 16));
  }
  __syncthreads();
  int* op = partial + (size_t)blockIdx.x * HWORDS;
  for (int i = threadIdx.x; i < HWORDS; i += HTHREADS) op[i] = h[i];
}

// ======== fused: reduce partials -> norms; in-place chunk-prefix; first-level scan ========
// One thread per packed WORD (2 nodes). word j -> nodes 2j, 2j+1.
__global__ __launch_bounds__(256) void reduce_norm_scan1(
    int* __restrict__ partial, float* __restrict__ nout, float* __restrict__ nin,
    int* __restrict__ rowptr, int* __restrict__ bsums, int N) {
  __shared__ int s[256];
  const int j = blockIdx.x * 256 + threadIdx.x;    // packed word id, < RANGES*HALF
  const int r = j / HALF;
  const int w = j % HALF;
  int* base = partial + (size_t)(r * PPR) * HWORDS;
  int sumO = 0, runI = 0;
#pragma unroll 8
  for (int p = 0; p < PPR; ++p) {
    sumO += base[(size_t)p * HWORDS + w];
    int vI = base[(size_t)p * HWORDS + HALF + w];
    base[(size_t)p * HWORDS + HALF + w] = runI;    // exclusive chunk-prefix (packed; no carry)
    runI += vI;
  }
  const int od0 = sumO & 0xFFFF, od1 = (sumO >> 16) & 0xFFFF;
  const int id0 = runI & 0xFFFF, id1 = (runI >> 16) & 0xFFFF;
  const int n0 = 2 * j, n1 = 2 * j + 1;
  if (n0 < N) {
    nout[n0] = od0 > 0 ? rsqrtf((float)od0) : 0.f;
    nin[n0]  = id0 > 0 ? rsqrtf((float)id0) : 0.f;
  }
  if (n1 < N) {
    nout[n1] = od1 > 0 ? rsqrtf((float)od1) : 0.f;
    nin[n1]  = id1 > 0 ? rsqrtf((float)id1) : 0.f;
  }
  // first-level exclusive scan of ideg (2 nodes per thread)
  const int local = id0 + id1;                      // 0 for nodes >= N (bins empty)
  int v = local;
  s[threadIdx.x] = v;
  __syncthreads();
#pragma unroll
  for (int off = 1; off < 256; off <<= 1) {
    int tv = 0;
    if (threadIdx.x >= off) tv = s[threadIdx.x - off];
    __syncthreads();
    if (threadIdx.x >= off) s[threadIdx.x] += tv;
    __syncthreads();
  }
  const int excl = s[threadIdx.x] - v;              // block-local exclusive start for node n0
  if (n0 < N) rowptr[n0] = excl;
  if (n1 < N) rowptr[n1] = excl + id0;
  if (threadIdx.x == 255) bsums[blockIdx.x] = s[255];
}

__global__ void scan_top(int* __restrict__ bsums, int nb) {
  __shared__ int s[256];
  __shared__ int run_s;
  if (threadIdx.x == 0) run_s = 0;
  __syncthreads();
  for (int base = 0; base < nb; base += 256) {
    int i = base + threadIdx.x;
    int v = (i < nb) ? bsums[i] : 0;
    s[threadIdx.x] = v;
    __syncthreads();
#pragma unroll
    for (int off = 1; off < 256; off <<= 1) {
      int tv = 0;
      if (threadIdx.x >= off) tv = s[threadIdx.x - off];
      __syncthreads();
      if (threadIdx.x >= off) s[threadIdx.x] += tv;
      __syncthreads();
    }
    int run = run_s;
    if (i < nb) bsums[i] = run + s[threadIdx.x] - v;
    __syncthreads();
    if (threadIdx.x == 0) run_s = run + s[255];
    __syncthreads();
  }
}

// rowptr += block offset (each scan block covered 512 nodes); rowptr[N] = E
__global__ void add_off(int* __restrict__ rowptr, const int* __restrict__ bsums, int N, int E) {
  int i = blockIdx.x * 512 + threadIdx.x;           // 512 threads/block
  if (i < N) rowptr[i] += bsums[blockIdx.x];
  if (blockIdx.x == 0 && threadIdx.x == 0) rowptr[N] = E;
}

// ======== CSR fill: LDS cursors, no global atomics; range = bid&7 for XCD L2 affinity ========
__global__ __launch_bounds__(HTHREADS) void fill_kernel(
    const int* __restrict__ src, const int* __restrict__ dst,
    const int* __restrict__ rowptr, const int* __restrict__ partial,
    int* __restrict__ csr, int N, int E) {
  __shared__ int cur[BINS];  // 25.6 KB absolute cursors
  const int r = blockIdx.x & 7;    // range -> XCD (empirical bid%8 round-robin)
  const int c = blockIdx.x >> 3;   // chunk
  const int lo = r * BINS;
  const int* pf = partial + (size_t)(r * PPR + c) * HWORDS + HALF;
  for (int n = threadIdx.x; n < BINS; n += HTHREADS) {
    int g = lo + n;
    int rp = (g < N) ? rowptr[g] : 0;
    int pw = pf[n >> 1];
    cur[n] = rp + ((pw >> ((n & 1) * 16)) & 0xFFFF);
  }
  __syncthreads();
  const int chunk = (E + PPR - 1) / PPR;
  const int e0 = c * chunk;
  const int e1 = min(E, e0 + chunk);
  for (int e = e0 + threadIdx.x; e < e1; e += HTHREADS) {
    int d = dst[e] - lo;
    if ((unsigned)d < (unsigned)BINS) {
      int pos = atomicAdd(&cur[d], 1);
      csr[pos] = src[e];
    }
  }
}

// ======== gather aggregation (16 lanes / node, float4, 4-way unrolled MLP) ========
// x pre-scaled by nout[src] on the producer side.
// L1: out = relu(acc*nin + bias); y = out * nout.  else: y = raw acc
template <bool L1>
__global__ void agg_kernel(const int* __restrict__ rowptr, const int* __restrict__ csr,
                           const float* __restrict__ x, const float* __restrict__ nin,
                           const float* __restrict__ bias, const float* __restrict__ nout,
                           float* __restrict__ y, float* __restrict__ out, int N) {
  int t = blockIdx.x * blockDim.x + threadIdx.x;
  int node = t >> 4;
  if (node >= N) return;
  int lane = t & 15;
  const int b = rowptr[node], e = rowptr[node + 1];
  float4 a0 = make_float4(0.f, 0.f, 0.f, 0.f);
  float4 a1 = make_float4(0.f, 0.f, 0.f, 0.f);
  float4 a2 = make_float4(0.f, 0.f, 0.f, 0.f);
  float4 a3 = make_float4(0.f, 0.f, 0.f, 0.f);
  const size_t lo4 = (size_t)lane * 4;
  int i = b;
  for (; i + 4 <= e; i += 4) {
    int s0 = csr[i + 0], s1 = csr[i + 1], s2 = csr[i + 2], s3 = csr[i + 3];
    float4 v0 = *reinterpret_cast<const float4*>(x + (size_t)s0 * 64 + lo4);
    float4 v1 = *reinterpret_cast<const float4*>(x + (size_t)s1 * 64 + lo4);
    float4 v2 = *reinterpret_cast<const float4*>(x + (size_t)s2 * 64 + lo4);
    float4 v3 = *reinterpret_cast<const float4*>(x + (size_t)s3 * 64 + lo4);
    a0.x += v0.x; a0.y += v0.y; a0.z += v0.z; a0.w += v0.w;
    a1.x += v1.x; a1.y += v1.y; a1.z += v1.z; a1.w += v1.w;
    a2.x += v2.x; a2.y += v2.y; a2.z += v2.z; a2.w += v2.w;
    a3.x += v3.x; a3.y += v3.y; a3.z += v3.z; a3.w += v3.w;
  }
  for (; i < e; ++i) {
    int s = csr[i];
    float4 v = *reinterpret_cast<const float4*>(x + (size_t)s * 64 + lo4);
    a0.x += v.x; a0.y += v.y; a0.z += v.z; a0.w += v.w;
  }
  float4 acc;
  acc.x = (a0.x + a1.x) + (a2.x + a3.x);
  acc.y = (a0.y + a1.y) + (a2.y + a3.y);
  acc.z = (a0.z + a1.z) + (a2.z + a3.z);
  acc.w = (a0.w + a1.w) + (a2.w + a3.w);

  size_t off = (size_t)node * 64 + lo4;
  if (L1) {
    float s = nin[node];
    float4 bb = *reinterpret_cast<const float4*>(bias + lo4);
    float4 h;
    h.x = fmaxf(acc.x * s + bb.x, 0.f);
    h.y = fmaxf(acc.y * s + bb.y, 0.f);
    h.z = fmaxf(acc.z * s + bb.z, 0.f);
    h.w = fmaxf(acc.w * s + bb.w, 0.f);
    *reinterpret_cast<float4*>(out + off) = h;
    float no = nout[node];
    h.x *= no; h.y *= no; h.z *= no; h.w *= no;
    *reinterpret_cast<float4*>(y + off) = h;
  } else {
    *reinterpret_cast<float4*>(y + off) = acc;
  }
}

// ======== tiled GEMM: C[M x 64] = (INSCALE? diag(nin)*A : A)[M x K] @ B[K x 64] ========
// FUSED: h = relu(AB + bias); out = max(out, h); C = (OUTS? h*nout : h) if WRITEC
// !FUSED: C = (OUTS? v*nout : v)
template <int K, bool INSCALE, bool FUSED, bool OUTS, bool WRITEC>
__global__ __launch_bounds__(256) void gemm_kernel(
    const float* __restrict__ A, const float* __restrict__ B,
    const float* __restrict__ nin, const float* __restrict__ bias,
    const float* __restrict__ nout,
    float* __restrict__ C, float* __restrict__ out, int M) {
  __shared__ float sA[64][K + 4];
  __shared__ float sB[K][64];
  const int t = threadIdx.x;
  const int row0 = blockIdx.x * 64;

  for (int i = t * 4; i < 64 * K; i += 256 * 4) {
    int r = i / K, c = i % K;
    int gr = row0 + r;
    float4 v = make_float4(0.f, 0.f, 0.f, 0.f);
    if (gr < M) {
      v = *reinterpret_cast<const float4*>(A + (size_t)gr * K + c);
      if (INSCALE) {
        float s = nin[gr];
        v.x *= s; v.y *= s; v.z *= s; v.w *= s;
      }
    }
    *reinterpret_cast<float4*>(&sA[r][c]) = v;
  }
  for (int i = t * 4; i < K * 64; i += 256 * 4) {
    *reinterpret_cast<float4*>(&sB[0][0] + i) = *reinterpret_cast<const float4*>(B + i);
  }
  __syncthreads();

  const int ty = t >> 4;
  const int tx = t & 15;
  float acc[4][4] = {};
#pragma unroll 8
  for (int k = 0; k < K; ++k) {
    float a[4];
#pragma unroll
    for (int i = 0; i < 4; ++i) a[i] = sA[ty * 4 + i][k];
    float4 b = *reinterpret_cast<float4*>(&sB[k][tx * 4]);
#pragma unroll
    for (int i = 0; i < 4; ++i) {
      acc[i][0] += a[i] * b.x;
      acc[i][1] += a[i] * b.y;
      acc[i][2] += a[i] * b.z;
      acc[i][3] += a[i] * b.w;
    }
  }

#pragma unroll
  for (int i = 0; i < 4; ++i) {
    int gr = row0 + ty * 4 + i;
    if (gr >= M) continue;
    float4 v = make_float4(acc[i][0], acc[i][1], acc[i][2], acc[i][3]);
    size_t off = (size_t)gr * 64 + tx * 4;
    if (FUSED) {
      float4 b = *reinterpret_cast<const float4*>(bias + tx * 4);
      float4 h;
      h.x = fmaxf(v.x + b.x, 0.f);
      h.y = fmaxf(v.y + b.y, 0.f);
      h.z = fmaxf(v.z + b.z, 0.f);
      h.w = fmaxf(v.w + b.w, 0.f);
      float4 o = *reinterpret_cast<float4*>(out + off);
      o.x = fmaxf(o.x, h.x);
      o.y = fmaxf(o.y, h.y);
      o.z = fmaxf(o.z, h.z);
      o.w = fmaxf(o.w, h.w);
      *reinterpret_cast<float4*>(out + off) = o;
      if (WRITEC) {
        if (OUTS) {
          float no = nout[gr];
          h.x *= no; h.y *= no; h.z *= no; h.w *= no;
        }
        *reinterpret_cast<float4*>(C + off) = h;
      }
    } else {
      if (OUTS) {
        float no = nout[gr];
        v.x *= no; v.y *= no; v.z *= no; v.w *= no;
      }
      *reinterpret_cast<float4*>(C + off) = v;
    }
  }
}

extern "C" void kernel_launch(void* const* d_in, const int* in_sizes, int n_in,
                              void* d_out, int out_size, void* d_ws, size_t ws_size,
                              hipStream_t stream) {
  const float* feat = (const float*)d_in[0];
  const int* src    = (const int*)d_in[1];
  const int* dst    = (const int*)d_in[2];
  const float* W1   = (const float*)d_in[3];
  const float* b1   = (const float*)d_in[4];
  const float* W2   = (const float*)d_in[5];
  const float* b2   = (const float*)d_in[6];
  const float* W3   = (const float*)d_in[7];
  const float* b3   = (const float*)d_in[8];
  float* out = (float*)d_out;

  const int N = in_sizes[0] / 128;
  const int E = in_sizes[1];

  // ---- workspace layout ----
  char* p = (char*)d_ws;
  float* nout   = (float*)p;          p += (size_t)N * 4;
  float* nin    = (float*)p;          p += (size_t)N * 4;
  int*   rowptr = (int*)p;            p += ((size_t)N + 8) * 4;
  int*   bsums  = (int*)p;            p += 1024 * 4;
  int*   csr    = (int*)p;            p += (size_t)E * 4;
  p = (char*)(((uintptr_t)p + 15) & ~(uintptr_t)15);
  float* bufA   = (float*)p;          p += (size_t)N * 64 * 4;
  float* bufB   = (float*)p;          p += (size_t)N * 64 * 4;
  // partial = RANGES*PPR*HWORDS*4 = 6.55 MB, aliased over bufA (12.8 MB).
  // Dead after fill_kernel, which completes before gemm1 writes bufA (same stream).
  int*   partial = (int*)bufA;

  const int nwords = RANGES * HALF;               // 25600 packed words
  const int nb = nwords / 256;                    // 100 scan blocks (512 nodes each)

  // ---- degrees + norms + rowptr + CSR (histogram path, no global atomics) ----
  hist_kernel<<<RANGES * PPR, HTHREADS, 0, stream>>>(src, dst, partial, E);
  reduce_norm_scan1<<<nb, 256, 0, stream>>>(partial, nout, nin, rowptr, bsums, N);
  scan_top<<<1, 256, 0, stream>>>(bsums, nb);
  add_off<<<nb, 512, 0, stream>>>(rowptr, bsums, N, E);
  fill_kernel<<<RANGES * PPR, HTHREADS, 0, stream>>>(src, dst, rowptr, partial, csr, N, E);

  const int gemm_blocks = (N + 63) / 64;
  const int agg_blocks  = (N * 16 + 255) / 256;

  // ---- layer 1: bufA = (feat@W1)*nout; agg -> out=h1; bufB = h1*nout ----
  gemm_kernel<128, false, false, true, true><<<gemm_blocks, 256, 0, stream>>>(
      feat, W1, nullptr, nullptr, nout, bufA, nullptr, N);
  agg_kernel<true><<<agg_blocks, 256, 0, stream>>>(rowptr, csr, bufA, nin, b1, nout, bufB, out, N);

  // ---- layer 2: bufA = agg(bufB); h2 = relu(nin*bufA@W2 + b2); out=max; bufB = h2*nout ----
  agg_kernel<false><<<agg_blocks, 256, 0, stream>>>(rowptr, csr, bufB, nullptr, nullptr, nullptr, bufA, nullptr, N);
  gemm_kernel<64, true, true, true, true><<<gemm_blocks, 256, 0, stream>>>(
      bufA, W2, nin, b2, nout, bufB, out, N);

  // ---- layer 3: bufA = agg(bufB); h3 = relu(nin*bufA@W3 + b3); out=max ----
  agg_kernel<false><<<agg_blocks, 256, 0, stream>>>(rowptr, csr, bufB, nullptr, nullptr, nullptr, bufA, nullptr, N);
  gemm_kernel<64, true, true, false, false><<<gemm_blocks, 256, 0, stream>>>(
      bufA, W3, nin, b3, nullptr, nullptr, out, N);
}

// Round 7
// 171.836 us; speedup vs baseline: 13.4426x; 1.2615x over previous
//
#include <hip/hip_runtime.h>

typedef _Float16 h16;
typedef __attribute__((ext_vector_type(4))) _Float16 half4;

#define RANGES 8
#define PPR    32            // chunks (partials per range)
#define HTHREADS 1024
#define BINS   6400          // nodes per range: 8*6400 = 51200 >= 50000; 6400 % 256 == 0
#define HALF   (BINS / 2)    // packed words per histogram (odeg or ideg)
#define HWORDS (BINS)        // words per partial block: HALF odeg + HALF ideg

// ======== histogram: 16-bit-packed LDS counters, per-(range,chunk) partials ========
__global__ __launch_bounds__(HTHREADS) void hist_kernel(const int* __restrict__ src,
                                                        const int* __restrict__ dst,
                                                        int* __restrict__ partial, int E) {
  __shared__ int h[HWORDS];  // 25.6 KB
  const int r = blockIdx.x >> 5;   // range
  const int c = blockIdx.x & 31;   // chunk
  for (int i = threadIdx.x; i < HWORDS; i += HTHREADS) h[i] = 0;
  __syncthreads();
  const int lo = r * BINS;
  const int chunk = (E + PPR - 1) / PPR;
  const int e0 = c * chunk;
  const int e1 = min(E, e0 + chunk);
  for (int e = e0 + threadIdx.x; e < e1; e += HTHREADS) {
    int s = src[e] - lo;
    if ((unsigned)s < (unsigned)BINS) atomicAdd(&h[s >> 1], 1 << ((s & 1) * 16));
    int d = dst[e] - lo;
    if ((unsigned)d < (unsigned)BINS) atomicAdd(&h[HALF + (d >> 1)], 1 << ((d & 1) * 16));
  }
  __syncthreads();
  int* op = partial + (size_t)blockIdx.x * HWORDS;
  for (int i = threadIdx.x; i < HWORDS; i += HTHREADS) op[i] = h[i];
}

// ======== fused: reduce partials -> norms; in-place chunk-prefix; first-level scan ========
__global__ __launch_bounds__(256) void reduce_norm_scan1(
    int* __restrict__ partial, float* __restrict__ nout, float* __restrict__ nin,
    int* __restrict__ rowptr, int* __restrict__ bsums, int N) {
  __shared__ int s[256];
  const int j = blockIdx.x * 256 + threadIdx.x;    // packed word id, < RANGES*HALF
  const int r = j / HALF;
  const int w = j % HALF;
  int* base = partial + (size_t)(r * PPR) * HWORDS;
  int sumO = 0, runI = 0;
#pragma unroll 8
  for (int p = 0; p < PPR; ++p) {
    sumO += base[(size_t)p * HWORDS + w];
    int vI = base[(size_t)p * HWORDS + HALF + w];
    base[(size_t)p * HWORDS + HALF + w] = runI;    // exclusive chunk-prefix (packed; no carry)
    runI += vI;
  }
  const int od0 = sumO & 0xFFFF, od1 = (sumO >> 16) & 0xFFFF;
  const int id0 = runI & 0xFFFF, id1 = (runI >> 16) & 0xFFFF;
  const int n0 = 2 * j, n1 = 2 * j + 1;
  if (n0 < N) {
    nout[n0] = od0 > 0 ? rsqrtf((float)od0) : 0.f;
    nin[n0]  = id0 > 0 ? rsqrtf((float)id0) : 0.f;
  }
  if (n1 < N) {
    nout[n1] = od1 > 0 ? rsqrtf((float)od1) : 0.f;
    nin[n1]  = id1 > 0 ? rsqrtf((float)id1) : 0.f;
  }
  const int local = id0 + id1;                      // 0 for nodes >= N (bins empty)
  int v = local;
  s[threadIdx.x] = v;
  __syncthreads();
#pragma unroll
  for (int off = 1; off < 256; off <<= 1) {
    int tv = 0;
    if (threadIdx.x >= off) tv = s[threadIdx.x - off];
    __syncthreads();
    if (threadIdx.x >= off) s[threadIdx.x] += tv;
    __syncthreads();
  }
  const int excl = s[threadIdx.x] - v;
  if (n0 < N) rowptr[n0] = excl;
  if (n1 < N) rowptr[n1] = excl + id0;
  if (threadIdx.x == 255) bsums[blockIdx.x] = s[255];
}

__global__ void scan_top(int* __restrict__ bsums, int nb) {
  __shared__ int s[256];
  __shared__ int run_s;
  if (threadIdx.x == 0) run_s = 0;
  __syncthreads();
  for (int base = 0; base < nb; base += 256) {
    int i = base + threadIdx.x;
    int v = (i < nb) ? bsums[i] : 0;
    s[threadIdx.x] = v;
    __syncthreads();
#pragma unroll
    for (int off = 1; off < 256; off <<= 1) {
      int tv = 0;
      if (threadIdx.x >= off) tv = s[threadIdx.x - off];
      __syncthreads();
      if (threadIdx.x >= off) s[threadIdx.x] += tv;
      __syncthreads();
    }
    int run = run_s;
    if (i < nb) bsums[i] = run + s[threadIdx.x] - v;
    __syncthreads();
    if (threadIdx.x == 0) run_s = run + s[255];
    __syncthreads();
  }
}

// rowptr += block offset (each scan block covered 512 nodes); rowptr[N] = E
__global__ void add_off(int* __restrict__ rowptr, const int* __restrict__ bsums, int N, int E) {
  int i = blockIdx.x * 512 + threadIdx.x;           // 512 threads/block
  if (i < N) rowptr[i] += bsums[blockIdx.x];
  if (blockIdx.x == 0 && threadIdx.x == 0) rowptr[N] = E;
}

// ======== CSR fill: LDS cursors, no global atomics; range = bid&7 for XCD L2 affinity ========
__global__ __launch_bounds__(HTHREADS) void fill_kernel(
    const int* __restrict__ src, const int* __restrict__ dst,
    const int* __restrict__ rowptr, const int* __restrict__ partial,
    int* __restrict__ csr, int N, int E) {
  __shared__ int cur[BINS];  // 25.6 KB absolute cursors
  const int r = blockIdx.x & 7;    // range -> XCD (empirical bid%8 round-robin)
  const int c = blockIdx.x >> 3;   // chunk
  const int lo = r * BINS;
  const int* pf = partial + (size_t)(r * PPR + c) * HWORDS + HALF;
  for (int n = threadIdx.x; n < BINS; n += HTHREADS) {
    int g = lo + n;
    int rp = (g < N) ? rowptr[g] : 0;
    int pw = pf[n >> 1];
    cur[n] = rp + ((pw >> ((n & 1) * 16)) & 0xFFFF);
  }
  __syncthreads();
  const int chunk = (E + PPR - 1) / PPR;
  const int e0 = c * chunk;
  const int e1 = min(E, e0 + chunk);
  for (int e = e0 + threadIdx.x; e < e1; e += HTHREADS) {
    int d = dst[e] - lo;
    if ((unsigned)d < (unsigned)BINS) {
      int pos = atomicAdd(&cur[d], 1);
      csr[pos] = src[e];
    }
  }
}

// ======== gather aggregation (16 lanes / node, half4 gathers, 4-way MLP unroll) ========
// x is fp16, pre-scaled by nout[src] on the producer side. fp32 accumulate.
// L1: out = relu(acc*nin + bias) [fp32]; y = half4(out * nout).  else: y = float4 raw acc
template <bool L1>
__global__ void agg_kernel(const int* __restrict__ rowptr, const int* __restrict__ csr,
                           const h16* __restrict__ x, const float* __restrict__ nin,
                           const float* __restrict__ bias, const float* __restrict__ nout,
                           void* __restrict__ y, float* __restrict__ out, int N) {
  int t = blockIdx.x * blockDim.x + threadIdx.x;
  int node = t >> 4;
  if (node >= N) return;
  int lane = t & 15;
  const int b = rowptr[node], e = rowptr[node + 1];
  const half4* xv = reinterpret_cast<const half4*>(x);
  float4 a0 = make_float4(0.f, 0.f, 0.f, 0.f);
  float4 a1 = make_float4(0.f, 0.f, 0.f, 0.f);
  float4 a2 = make_float4(0.f, 0.f, 0.f, 0.f);
  float4 a3 = make_float4(0.f, 0.f, 0.f, 0.f);
  int i = b;
  for (; i + 4 <= e; i += 4) {
    int s0 = csr[i + 0], s1 = csr[i + 1], s2 = csr[i + 2], s3 = csr[i + 3];
    half4 v0 = xv[(size_t)s0 * 16 + lane];
    half4 v1 = xv[(size_t)s1 * 16 + lane];
    half4 v2 = xv[(size_t)s2 * 16 + lane];
    half4 v3 = xv[(size_t)s3 * 16 + lane];
    a0.x += (float)v0.x; a0.y += (float)v0.y; a0.z += (float)v0.z; a0.w += (float)v0.w;
    a1.x += (float)v1.x; a1.y += (float)v1.y; a1.z += (float)v1.z; a1.w += (float)v1.w;
    a2.x += (float)v2.x; a2.y += (float)v2.y; a2.z += (float)v2.z; a2.w += (float)v2.w;
    a3.x += (float)v3.x; a3.y += (float)v3.y; a3.z += (float)v3.z; a3.w += (float)v3.w;
  }
  for (; i < e; ++i) {
    int s = csr[i];
    half4 v = xv[(size_t)s * 16 + lane];
    a0.x += (float)v.x; a0.y += (float)v.y; a0.z += (float)v.z; a0.w += (float)v.w;
  }
  float4 acc;
  acc.x = (a0.x + a1.x) + (a2.x + a3.x);
  acc.y = (a0.y + a1.y) + (a2.y + a3.y);
  acc.z = (a0.z + a1.z) + (a2.z + a3.z);
  acc.w = (a0.w + a1.w) + (a2.w + a3.w);

  if (L1) {
    float s = nin[node];
    float4 bb = *reinterpret_cast<const float4*>(bias + lane * 4);
    float4 h;
    h.x = fmaxf(acc.x * s + bb.x, 0.f);
    h.y = fmaxf(acc.y * s + bb.y, 0.f);
    h.z = fmaxf(acc.z * s + bb.z, 0.f);
    h.w = fmaxf(acc.w * s + bb.w, 0.f);
    *reinterpret_cast<float4*>(out + (size_t)node * 64 + lane * 4) = h;
    float no = nout[node];
    half4 hv;
    hv.x = (h16)(h.x * no); hv.y = (h16)(h.y * no);
    hv.z = (h16)(h.z * no); hv.w = (h16)(h.w * no);
    reinterpret_cast<half4*>(y)[(size_t)node * 16 + lane] = hv;
  } else {
    *reinterpret_cast<float4*>((float*)y + (size_t)node * 64 + lane * 4) = acc;
  }
}

// ======== tiled GEMM: P[M x 64] = (INSCALE? diag(nin)*A : A)[M x K] @ B[K x 64] ========
// FUSED: h = relu(P + bias); out = max(out, h). Else h = P.
// WRITEC: C(half4) = h * nout   (the fp16 gather table for the next aggregation)
template <int K, bool INSCALE, bool FUSED, bool WRITEC>
__global__ __launch_bounds__(256) void gemm_kernel(
    const float* __restrict__ A, const float* __restrict__ B,
    const float* __restrict__ nin, const float* __restrict__ bias,
    const float* __restrict__ nout,
    half4* __restrict__ C, float* __restrict__ out, int M) {
  __shared__ float sA[64][K + 4];
  __shared__ float sB[K][64];
  const int t = threadIdx.x;
  const int row0 = blockIdx.x * 64;

  for (int i = t * 4; i < 64 * K; i += 256 * 4) {
    int r = i / K, c = i % K;
    int gr = row0 + r;
    float4 v = make_float4(0.f, 0.f, 0.f, 0.f);
    if (gr < M) {
      v = *reinterpret_cast<const float4*>(A + (size_t)gr * K + c);
      if (INSCALE) {
        float s = nin[gr];
        v.x *= s; v.y *= s; v.z *= s; v.w *= s;
      }
    }
    *reinterpret_cast<float4*>(&sA[r][c]) = v;
  }
  for (int i = t * 4; i < K * 64; i += 256 * 4) {
    *reinterpret_cast<float4*>(&sB[0][0] + i) = *reinterpret_cast<const float4*>(B + i);
  }
  __syncthreads();

  const int ty = t >> 4;
  const int tx = t & 15;
  float acc[4][4] = {};
#pragma unroll 8
  for (int k = 0; k < K; ++k) {
    float a[4];
#pragma unroll
    for (int i = 0; i < 4; ++i) a[i] = sA[ty * 4 + i][k];
    float4 b = *reinterpret_cast<float4*>(&sB[k][tx * 4]);
#pragma unroll
    for (int i = 0; i < 4; ++i) {
      acc[i][0] += a[i] * b.x;
      acc[i][1] += a[i] * b.y;
      acc[i][2] += a[i] * b.z;
      acc[i][3] += a[i] * b.w;
    }
  }

#pragma unroll
  for (int i = 0; i < 4; ++i) {
    int gr = row0 + ty * 4 + i;
    if (gr >= M) continue;
    float4 h = make_float4(acc[i][0], acc[i][1], acc[i][2], acc[i][3]);
    if (FUSED) {
      float4 b = *reinterpret_cast<const float4*>(bias + tx * 4);
      h.x = fmaxf(h.x + b.x, 0.f);
      h.y = fmaxf(h.y + b.y, 0.f);
      h.z = fmaxf(h.z + b.z, 0.f);
      h.w = fmaxf(h.w + b.w, 0.f);
      size_t off = (size_t)gr * 64 + tx * 4;
      float4 o = *reinterpret_cast<float4*>(out + off);
      o.x = fmaxf(o.x, h.x);
      o.y = fmaxf(o.y, h.y);
      o.z = fmaxf(o.z, h.z);
      o.w = fmaxf(o.w, h.w);
      *reinterpret_cast<float4*>(out + off) = o;
    }
    if (WRITEC) {
      float no = nout[gr];
      half4 hv;
      hv.x = (h16)(h.x * no); hv.y = (h16)(h.y * no);
      hv.z = (h16)(h.z * no); hv.w = (h16)(h.w * no);
      C[(size_t)gr * 16 + tx] = hv;
    }
  }
}

extern "C" void kernel_launch(void* const* d_in, const int* in_sizes, int n_in,
                              void* d_out, int out_size, void* d_ws, size_t ws_size,
                              hipStream_t stream) {
  const float* feat = (const float*)d_in[0];
  const int* src    = (const int*)d_in[1];
  const int* dst    = (const int*)d_in[2];
  const float* W1   = (const float*)d_in[3];
  const float* b1   = (const float*)d_in[4];
  const float* W2   = (const float*)d_in[5];
  const float* b2   = (const float*)d_in[6];
  const float* W3   = (const float*)d_in[7];
  const float* b3   = (const float*)d_in[8];
  float* out = (float*)d_out;

  const int N = in_sizes[0] / 128;
  const int E = in_sizes[1];

  // ---- workspace layout ----
  char* p = (char*)d_ws;
  float* nout   = (float*)p;          p += (size_t)N * 4;
  float* nin    = (float*)p;          p += (size_t)N * 4;
  int*   rowptr = (int*)p;            p += ((size_t)N + 8) * 4;
  int*   bsums  = (int*)p;            p += 1024 * 4;
  int*   csr    = (int*)p;            p += (size_t)E * 4;
  p = (char*)(((uintptr_t)p + 15) & ~(uintptr_t)15);
  h16*   bufAh  = (h16*)p;            p += (size_t)N * 64 * 2;   // fp16 gather table (6.4 MB)
  h16*   bufBh  = (h16*)p;            p += (size_t)N * 64 * 2;   // fp16 gather table (6.4 MB)
  p = (char*)(((uintptr_t)p + 15) & ~(uintptr_t)15);
  float* bufF   = (float*)p;          p += (size_t)N * 64 * 4;   // fp32 dense agg output (12.8 MB)
  // partial = RANGES*PPR*HWORDS*4 = 6.55 MB, aliased over bufF (12.8 MB).
  // Dead after fill_kernel, which completes before agg2 writes bufF (same stream).
  int*   partial = (int*)bufF;

  const int nwords = RANGES * HALF;               // 25600 packed words
  const int nb = nwords / 256;                    // 100 scan blocks (512 nodes each)

  // ---- degrees + norms + rowptr + CSR (histogram path, no global atomics) ----
  hist_kernel<<<RANGES * PPR, HTHREADS, 0, stream>>>(src, dst, partial, E);
  reduce_norm_scan1<<<nb, 256, 0, stream>>>(partial, nout, nin, rowptr, bsums, N);
  scan_top<<<1, 256, 0, stream>>>(bsums, nb);
  add_off<<<nb, 512, 0, stream>>>(rowptr, bsums, N, E);
  fill_kernel<<<RANGES * PPR, HTHREADS, 0, stream>>>(src, dst, rowptr, partial, csr, N, E);

  const int gemm_blocks = (N + 63) / 64;
  const int agg_blocks  = (N * 16 + 255) / 256;

  // ---- layer 1: bufAh = half(feat@W1 * nout); agg1 -> out=h1 (fp32), bufBh = half(h1*nout) ----
  gemm_kernel<128, false, false, true><<<gemm_blocks, 256, 0, stream>>>(
      feat, W1, nullptr, nullptr, nout, (half4*)bufAh, nullptr, N);
  agg_kernel<true><<<agg_blocks, 256, 0, stream>>>(rowptr, csr, bufAh, nin, b1, nout, bufBh, out, N);

  // ---- layer 2: bufF = agg(bufBh); h2 = relu(nin*bufF@W2 + b2); out=max; bufAh = half(h2*nout) ----
  agg_kernel<false><<<agg_blocks, 256, 0, stream>>>(rowptr, csr, bufBh, nullptr, nullptr, nullptr, bufF, nullptr, N);
  gemm_kernel<64, true, true, true><<<gemm_blocks, 256, 0, stream>>>(
      bufF, W2, nin, b2, nout, (half4*)bufAh, out, N);

  // ---- layer 3: bufF = agg(bufAh); h3 = relu(nin*bufF@W3 + b3); out=max ----
  agg_kernel<false><<<agg_blocks, 256, 0, stream>>>(rowptr, csr, bufAh, nullptr, nullptr, nullptr, bufF, nullptr, N);
  gemm_kernel<64, true, true, false><<<gemm_blocks, 256, 0, stream>>>(
      bufF, W3, nin, b3, nullptr, nullptr, out, N);
}

// Round 8
// 167.338 us; speedup vs baseline: 13.8040x; 1.0269x over previous
//
#include <hip/hip_runtime.h>

typedef _Float16 h16;
typedef __attribute__((ext_vector_type(4))) _Float16 half4;
typedef __attribute__((ext_vector_type(8))) _Float16 half8;
typedef __attribute__((ext_vector_type(8))) float float8;

#define RANGES 8
#define PPR    32            // chunks (partials per range)
#define HTHREADS 1024
#define BINS   6400          // nodes per range: 8*6400 = 51200 >= 50000; 6400 % 256 == 0
#define HALF   (BINS / 2)    // packed words per histogram (odeg or ideg)
#define HWORDS (BINS)        // words per partial block: HALF odeg + HALF ideg

// ======== histogram: 16-bit-packed LDS counters, per-(range,chunk) partials ========
__global__ __launch_bounds__(HTHREADS) void hist_kernel(const int* __restrict__ src,
                                                        const int* __restrict__ dst,
                                                        int* __restrict__ partial, int E) {
  __shared__ int h[HWORDS];  // 25.6 KB
  const int r = blockIdx.x >> 5;   // range
  const int c = blockIdx.x & 31;   // chunk
  for (int i = threadIdx.x; i < HWORDS; i += HTHREADS) h[i] = 0;
  __syncthreads();
  const int lo = r * BINS;
  const int chunk = (E + PPR - 1) / PPR;
  const int e0 = c * chunk;
  const int e1 = min(E, e0 + chunk);
  for (int e = e0 + threadIdx.x; e < e1; e += HTHREADS) {
    int s = src[e] - lo;
    if ((unsigned)s < (unsigned)BINS) atomicAdd(&h[s >> 1], 1 << ((s & 1) * 16));
    int d = dst[e] - lo;
    if ((unsigned)d < (unsigned)BINS) atomicAdd(&h[HALF + (d >> 1)], 1 << ((d & 1) * 16));
  }
  __syncthreads();
  int* op = partial + (size_t)blockIdx.x * HWORDS;
  for (int i = threadIdx.x; i < HWORDS; i += HTHREADS) op[i] = h[i];
}

// ======== fused: reduce partials -> norms; in-place chunk-prefix; first-level scan ========
__global__ __launch_bounds__(256) void reduce_norm_scan1(
    int* __restrict__ partial, float* __restrict__ nout, float* __restrict__ nin,
    int* __restrict__ rowptr, int* __restrict__ bsums, int N) {
  __shared__ int s[256];
  const int j = blockIdx.x * 256 + threadIdx.x;    // packed word id, < RANGES*HALF
  const int r = j / HALF;
  const int w = j % HALF;
  int* base = partial + (size_t)(r * PPR) * HWORDS;
  int sumO = 0, runI = 0;
#pragma unroll 8
  for (int p = 0; p < PPR; ++p) {
    sumO += base[(size_t)p * HWORDS + w];
    int vI = base[(size_t)p * HWORDS + HALF + w];
    base[(size_t)p * HWORDS + HALF + w] = runI;    // exclusive chunk-prefix (packed; no carry)
    runI += vI;
  }
  const int od0 = sumO & 0xFFFF, od1 = (sumO >> 16) & 0xFFFF;
  const int id0 = runI & 0xFFFF, id1 = (runI >> 16) & 0xFFFF;
  const int n0 = 2 * j, n1 = 2 * j + 1;
  if (n0 < N) {
    nout[n0] = od0 > 0 ? rsqrtf((float)od0) : 0.f;
    nin[n0]  = id0 > 0 ? rsqrtf((float)id0) : 0.f;
  }
  if (n1 < N) {
    nout[n1] = od1 > 0 ? rsqrtf((float)od1) : 0.f;
    nin[n1]  = id1 > 0 ? rsqrtf((float)id1) : 0.f;
  }
  const int local = id0 + id1;                      // 0 for nodes >= N (bins empty)
  int v = local;
  s[threadIdx.x] = v;
  __syncthreads();
#pragma unroll
  for (int off = 1; off < 256; off <<= 1) {
    int tv = 0;
    if (threadIdx.x >= off) tv = s[threadIdx.x - off];
    __syncthreads();
    if (threadIdx.x >= off) s[threadIdx.x] += tv;
    __syncthreads();
  }
  const int excl = s[threadIdx.x] - v;
  if (n0 < N) rowptr[n0] = excl;
  if (n1 < N) rowptr[n1] = excl + id0;
  if (threadIdx.x == 255) bsums[blockIdx.x] = s[255];
}

// ======== top scan folded into add_off: every block scans bsums[0..nb) in LDS ========
__global__ __launch_bounds__(512) void add_off2(int* __restrict__ rowptr,
                                                const int* __restrict__ bsums,
                                                int N, int E, int nb) {
  __shared__ int s[128];
  const int tid = threadIdx.x;
  if (tid < 128) s[tid] = (tid < nb) ? bsums[tid] : 0;
  __syncthreads();
#pragma unroll
  for (int off = 1; off < 128; off <<= 1) {
    int v = 0;
    if (tid < 128 && tid >= off) v = s[tid - off];
    __syncthreads();
    if (tid < 128 && tid >= off) s[tid] += v;
    __syncthreads();
  }
  const int base = (blockIdx.x == 0) ? 0 : s[blockIdx.x - 1];  // exclusive block offset
  const int i = blockIdx.x * 512 + tid;
  if (i < N) rowptr[i] += base;
  if (blockIdx.x == 0 && tid == 0) rowptr[N] = E;
}

// ======== CSR fill: LDS cursors, no global atomics; range = bid&7 for XCD L2 affinity ========
__global__ __launch_bounds__(HTHREADS) void fill_kernel(
    const int* __restrict__ src, const int* __restrict__ dst,
    const int* __restrict__ rowptr, const int* __restrict__ partial,
    int* __restrict__ csr, int N, int E) {
  __shared__ int cur[BINS];  // 25.6 KB absolute cursors
  const int r = blockIdx.x & 7;    // range -> XCD (empirical bid%8 round-robin)
  const int c = blockIdx.x >> 3;   // chunk
  const int lo = r * BINS;
  const int* pf = partial + (size_t)(r * PPR + c) * HWORDS + HALF;
  for (int n = threadIdx.x; n < BINS; n += HTHREADS) {
    int g = lo + n;
    int rp = (g < N) ? rowptr[g] : 0;
    int pw = pf[n >> 1];
    cur[n] = rp + ((pw >> ((n & 1) * 16)) & 0xFFFF);
  }
  __syncthreads();
  const int chunk = (E + PPR - 1) / PPR;
  const int e0 = c * chunk;
  const int e1 = min(E, e0 + chunk);
  for (int e = e0 + threadIdx.x; e < e1; e += HTHREADS) {
    int d = dst[e] - lo;
    if ((unsigned)d < (unsigned)BINS) {
      int pos = atomicAdd(&cur[d], 1);
      csr[pos] = src[e];
    }
  }
}

// ======== shared gather core: 8 lanes/node, half8 (16B) loads, 4-way MLP unroll ========
__device__ __forceinline__ float8 gather_row(const int* __restrict__ rowptr,
                                             const int* __restrict__ csr,
                                             const half8* __restrict__ xv,
                                             int node, int lane) {
  const int b = rowptr[node], e = rowptr[node + 1];
  float8 a0 = 0.f, a1 = 0.f, a2 = 0.f, a3 = 0.f;
  int i = b;
  for (; i + 4 <= e; i += 4) {
    int s0 = csr[i + 0], s1 = csr[i + 1], s2 = csr[i + 2], s3 = csr[i + 3];
    half8 v0 = xv[(size_t)s0 * 8 + lane];
    half8 v1 = xv[(size_t)s1 * 8 + lane];
    half8 v2 = xv[(size_t)s2 * 8 + lane];
    half8 v3 = xv[(size_t)s3 * 8 + lane];
#pragma unroll
    for (int j = 0; j < 8; ++j) {
      a0[j] += (float)v0[j]; a1[j] += (float)v1[j];
      a2[j] += (float)v2[j]; a3[j] += (float)v3[j];
    }
  }
  for (; i < e; ++i) {
    int s = csr[i];
    half8 v = xv[(size_t)s * 8 + lane];
#pragma unroll
    for (int j = 0; j < 8; ++j) a0[j] += (float)v[j];
  }
#pragma unroll
  for (int j = 0; j < 8; ++j) a0[j] = (a0[j] + a1[j]) + (a2[j] + a3[j]);
  return a0;
}

// ======== layer-1 aggregation: gather fp16 table -> out = relu(acc*nin+b1); y = fp16(out*nout)
__global__ __launch_bounds__(512) void agg1_kernel(
    const int* __restrict__ rowptr, const int* __restrict__ csr,
    const h16* __restrict__ x, const float* __restrict__ nin,
    const float* __restrict__ bias, const float* __restrict__ nout,
    half8* __restrict__ y, float* __restrict__ out, int N) {
  int t = blockIdx.x * 512 + threadIdx.x;
  int node = t >> 3;
  if (node >= N) return;
  int lane = t & 7;
  float8 acc = gather_row(rowptr, csr, reinterpret_cast<const half8*>(x), node, lane);
  const float s = nin[node];
  const float no = nout[node];
  float8 h;
  half8 hv;
#pragma unroll
  for (int j = 0; j < 8; ++j) {
    h[j] = fmaxf(acc[j] * s + bias[lane * 8 + j], 0.f);
    hv[j] = (h16)(h[j] * no);
  }
  float4 o0 = make_float4(h[0], h[1], h[2], h[3]);
  float4 o1 = make_float4(h[4], h[5], h[6], h[7]);
  size_t off = (size_t)node * 64 + lane * 8;
  *reinterpret_cast<float4*>(out + off)     = o0;
  *reinterpret_cast<float4*>(out + off + 4) = o1;
  y[(size_t)node * 8 + lane] = hv;
}

// ======== fused layer (2,3): gather -> sA(nin-scaled, LDS) -> @W -> relu/max/out [, fp16 table]
template <bool WRITEC>
__global__ __launch_bounds__(512) void fused_layer(
    const int* __restrict__ rowptr, const int* __restrict__ csr,
    const h16* __restrict__ x, const float* __restrict__ W,
    const float* __restrict__ nin, const float* __restrict__ bias,
    const float* __restrict__ nout,
    half4* __restrict__ C, float* __restrict__ out, int N) {
  __shared__ float sA[64][68];   // gathered+nin-scaled A tile (aligned 16B rows)
  __shared__ float sB[64][64];   // W
  const int t = threadIdx.x;
  const int row0 = blockIdx.x * 64;

  // stage W
  for (int i = t * 4; i < 64 * 64; i += 512 * 4)
    *reinterpret_cast<float4*>(&sB[0][0] + i) = *reinterpret_cast<const float4*>(W + i);

  // gather phase: 8 lanes/node, 64 nodes/block
  {
    const int node = t >> 3, lane = t & 7;
    const int g = row0 + node;
    float8 acc = 0.f;
    float s = 0.f;
    if (g < N) {
      acc = gather_row(rowptr, csr, reinterpret_cast<const half8*>(x), g, lane);
      s = nin[g];
    }
    float4 w0 = make_float4(acc[0] * s, acc[1] * s, acc[2] * s, acc[3] * s);
    float4 w1 = make_float4(acc[4] * s, acc[5] * s, acc[6] * s, acc[7] * s);
    *reinterpret_cast<float4*>(&sA[node][lane * 8])     = w0;
    *reinterpret_cast<float4*>(&sA[node][lane * 8 + 4]) = w1;
  }
  __syncthreads();

  // matmul phase: 2 rows x 4 cols per thread
  const int tx = t & 15;        // col group (4 cols)
  const int ry = t >> 4;        // 0..31 -> rows 2ry, 2ry+1
  const int r0 = 2 * ry, r1 = 2 * ry + 1;
  float4 acc0 = make_float4(0.f, 0.f, 0.f, 0.f);
  float4 acc1 = make_float4(0.f, 0.f, 0.f, 0.f);
#pragma unroll 8
  for (int k = 0; k < 64; ++k) {
    float a0 = sA[r0][k], a1 = sA[r1][k];
    float4 b = *reinterpret_cast<float4*>(&sB[k][tx * 4]);
    acc0.x += a0 * b.x; acc0.y += a0 * b.y; acc0.z += a0 * b.z; acc0.w += a0 * b.w;
    acc1.x += a1 * b.x; acc1.y += a1 * b.y; acc1.z += a1 * b.z; acc1.w += a1 * b.w;
  }

  const float4 bb = *reinterpret_cast<const float4*>(bias + tx * 4);
#pragma unroll
  for (int rr = 0; rr < 2; ++rr) {
    const int gr = row0 + (rr ? r1 : r0);
    if (gr >= N) continue;
    float4 v = rr ? acc1 : acc0;
    v.x = fmaxf(v.x + bb.x, 0.f);
    v.y = fmaxf(v.y + bb.y, 0.f);
    v.z = fmaxf(v.z + bb.z, 0.f);
    v.w = fmaxf(v.w + bb.w, 0.f);
    size_t off = (size_t)gr * 64 + tx * 4;
    float4 o = *reinterpret_cast<float4*>(out + off);
    o.x = fmaxf(o.x, v.x);
    o.y = fmaxf(o.y, v.y);
    o.z = fmaxf(o.z, v.z);
    o.w = fmaxf(o.w, v.w);
    *reinterpret_cast<float4*>(out + off) = o;
    if (WRITEC) {
      float no = nout[gr];
      half4 hv;
      hv.x = (h16)(v.x * no); hv.y = (h16)(v.y * no);
      hv.z = (h16)(v.z * no); hv.w = (h16)(v.w * no);
      C[(size_t)gr * 16 + tx] = hv;
    }
  }
}

// ======== gemm1: X1[M x 64] = A[M x 128] @ B[128 x 64]; C(fp16) = X1 * nout ========
__global__ __launch_bounds__(256) void gemm1_kernel(
    const float* __restrict__ A, const float* __restrict__ B,
    const float* __restrict__ nout, half4* __restrict__ C, int M) {
  __shared__ float sA[64][132];
  __shared__ float sB[128][64];
  const int t = threadIdx.x;
  const int row0 = blockIdx.x * 64;

  for (int i = t * 4; i < 64 * 128; i += 256 * 4) {
    int r = i / 128, c = i % 128;
    int gr = row0 + r;
    float4 v = make_float4(0.f, 0.f, 0.f, 0.f);
    if (gr < M) v = *reinterpret_cast<const float4*>(A + (size_t)gr * 128 + c);
    *reinterpret_cast<float4*>(&sA[r][c]) = v;
  }
  for (int i = t * 4; i < 128 * 64; i += 256 * 4)
    *reinterpret_cast<float4*>(&sB[0][0] + i) = *reinterpret_cast<const float4*>(B + i);
  __syncthreads();

  const int ty = t >> 4;
  const int tx = t & 15;
  float acc[4][4] = {};
#pragma unroll 8
  for (int k = 0; k < 128; ++k) {
    float a[4];
#pragma unroll
    for (int i = 0; i < 4; ++i) a[i] = sA[ty * 4 + i][k];
    float4 b = *reinterpret_cast<float4*>(&sB[k][tx * 4]);
#pragma unroll
    for (int i = 0; i < 4; ++i) {
      acc[i][0] += a[i] * b.x;
      acc[i][1] += a[i] * b.y;
      acc[i][2] += a[i] * b.z;
      acc[i][3] += a[i] * b.w;
    }
  }

#pragma unroll
  for (int i = 0; i < 4; ++i) {
    int gr = row0 + ty * 4 + i;
    if (gr >= M) continue;
    float no = nout[gr];
    half4 hv;
    hv.x = (h16)(acc[i][0] * no); hv.y = (h16)(acc[i][1] * no);
    hv.z = (h16)(acc[i][2] * no); hv.w = (h16)(acc[i][3] * no);
    C[(size_t)gr * 16 + tx] = hv;
  }
}

extern "C" void kernel_launch(void* const* d_in, const int* in_sizes, int n_in,
                              void* d_out, int out_size, void* d_ws, size_t ws_size,
                              hipStream_t stream) {
  const float* feat = (const float*)d_in[0];
  const int* src    = (const int*)d_in[1];
  const int* dst    = (const int*)d_in[2];
  const float* W1   = (const float*)d_in[3];
  const float* b1   = (const float*)d_in[4];
  const float* W2   = (const float*)d_in[5];
  const float* b2   = (const float*)d_in[6];
  const float* W3   = (const float*)d_in[7];
  const float* b3   = (const float*)d_in[8];
  float* out = (float*)d_out;

  const int N = in_sizes[0] / 128;
  const int E = in_sizes[1];

  // ---- workspace layout ----
  char* p = (char*)d_ws;
  float* nout   = (float*)p;          p += (size_t)N * 4;
  float* nin    = (float*)p;          p += (size_t)N * 4;
  int*   rowptr = (int*)p;            p += ((size_t)N + 8) * 4;
  int*   bsums  = (int*)p;            p += 1024 * 4;
  int*   csr    = (int*)p;            p += (size_t)E * 4;
  p = (char*)(((uintptr_t)p + 15) & ~(uintptr_t)15);
  h16*   bufAh  = (h16*)p;            p += (size_t)N * 64 * 2;   // fp16 gather table (6.4 MB)
  h16*   bufBh  = (h16*)p;            p += (size_t)N * 64 * 2;   // fp16 gather table (6.4 MB)
  // partial = RANGES*PPR*HWORDS*4 = 6.55 MB, aliased over bufAh+start of bufBh.
  // Dead after fill_kernel, which completes before gemm1 writes bufAh (same stream).
  int*   partial = (int*)bufAh;

  const int nwords = RANGES * HALF;               // 25600 packed words
  const int nb = nwords / 256;                    // 100 scan blocks (512 nodes each)

  // ---- degrees + norms + rowptr + CSR (histogram path, no global atomics) ----
  hist_kernel<<<RANGES * PPR, HTHREADS, 0, stream>>>(src, dst, partial, E);
  reduce_norm_scan1<<<nb, 256, 0, stream>>>(partial, nout, nin, rowptr, bsums, N);
  add_off2<<<nb, 512, 0, stream>>>(rowptr, bsums, N, E, nb);
  fill_kernel<<<RANGES * PPR, HTHREADS, 0, stream>>>(src, dst, rowptr, partial, csr, N, E);

  const int gemm_blocks  = (N + 63) / 64;                 // 782
  const int agg1_blocks  = (int)(((size_t)N * 8 + 511) / 512);

  // ---- layer 1: bufAh = half(feat@W1 * nout); agg1 -> out=h1 (fp32), bufBh = half(h1*nout) ----
  gemm1_kernel<<<gemm_blocks, 256, 0, stream>>>(feat, W1, nout, (half4*)bufAh, N);
  agg1_kernel<<<agg1_blocks, 512, 0, stream>>>(rowptr, csr, bufAh, nin, b1, nout,
                                               (half8*)bufBh, out, N);

  // ---- layer 2 fused: gather(bufBh) -> @W2 -> relu/max/out; bufAh = half(h2*nout) ----
  fused_layer<true><<<gemm_blocks, 512, 0, stream>>>(rowptr, csr, bufBh, W2, nin, b2, nout,
                                                     (half4*)bufAh, out, N);

  // ---- layer 3 fused: gather(bufAh) -> @W3 -> relu/max/out ----
  fused_layer<false><<<gemm_blocks, 512, 0, stream>>>(rowptr, csr, bufAh, W3, nin, b3, nullptr,
                                                      nullptr, out, N);
}